// Round 5
// baseline (582.102 us; speedup 1.0000x reference)
//
#include <hip/hip_runtime.h>

#define N_NODES  50000
#define N_EDGES  600000
#define N_GRAPHS 512

#define SCAN_N   (N_NODES + 1)
#define SCAN_BPB 1024                                   // elements per scan block
#define SCAN_NB  ((SCAN_N + SCAN_BPB - 1) / SCAN_BPB)   // 49

static __device__ __forceinline__ float4 f4zero() { return make_float4(0.f, 0.f, 0.f, 0.f); }

// ---------------- tiny init kernels (avoid hipMemsetAsync under capture) ----

__global__ void zero_int_kernel(int* __restrict__ p, int n) {
    int i = blockIdx.x * blockDim.x + threadIdx.x;
    if (i < n) p[i] = 0;
}
__global__ void zero_float_kernel(float* __restrict__ p, int n) {
    int i = blockIdx.x * blockDim.x + threadIdx.x;
    if (i < n) p[i] = 0.f;
}

// ---------------- CSR build ----------------

__global__ void hist_kernel(const int* __restrict__ edge, int* __restrict__ rowptr) {
    int e = blockIdx.x * blockDim.x + threadIdx.x;
    if (e < N_EDGES) atomicAdd(&rowptr[edge[N_EDGES + e] + 1], 1);
}

// --- hierarchical 3-pass inclusive scan over data[0..SCAN_N-1] -------------
// pass 1: per-block (1024 elems) reduction -> bsum[49]
__global__ void scan_reduce_kernel(const int* __restrict__ data, int* __restrict__ bsum) {
    __shared__ int red[256];
    int b = blockIdx.x, t = threadIdx.x;
    int base = b * SCAN_BPB + t * 4;
    int s = 0;
#pragma unroll
    for (int j = 0; j < 4; ++j) {
        int idx = base + j;
        if (idx < SCAN_N) s += data[idx];
    }
    red[t] = s;
    __syncthreads();
    for (int off = 128; off > 0; off >>= 1) {
        if (t < off) red[t] += red[t + off];
        __syncthreads();
    }
    if (t == 0) bsum[b] = red[0];
}

// pass 2: one tiny block converts bsum[] to exclusive block offsets in place
__global__ void scan_sums_kernel(int* __restrict__ bsum) {
    __shared__ int sh[SCAN_NB];
    int t = threadIdx.x;
    if (t < SCAN_NB) sh[t] = bsum[t];
    __syncthreads();
    if (t == 0) {
        int run = 0;
        for (int i = 0; i < SCAN_NB; ++i) { int v = sh[i]; sh[i] = run; run += v; }
    }
    __syncthreads();
    if (t < SCAN_NB) bsum[t] = sh[t];
}

// pass 3: per-block LDS scan + exclusive block offset, in-place inclusive scan
__global__ void scan_apply_kernel(int* __restrict__ data, const int* __restrict__ bexc) {
    __shared__ int th[256];
    int b = blockIdx.x, t = threadIdx.x;
    int base = b * SCAN_BPB + t * 4;
    int v[4];
    int s = 0;
#pragma unroll
    for (int j = 0; j < 4; ++j) {
        int idx = base + j;
        v[j] = (idx < SCAN_N) ? data[idx] : 0;
        s += v[j];
    }
    th[t] = s;
    __syncthreads();
    // Hillis-Steele inclusive scan over 256 thread sums
    for (int off = 1; off < 256; off <<= 1) {
        int x = (t >= off) ? th[t - off] : 0;
        __syncthreads();
        th[t] += x;
        __syncthreads();
    }
    int run = bexc[b] + th[t] - s;  // exclusive prefix for this thread
#pragma unroll
    for (int j = 0; j < 4; ++j) {
        int idx = base + j;
        run += v[j];
        if (idx < SCAN_N) data[idx] = run;
    }
}

__global__ void cursor_kernel(const int* __restrict__ rowptr, int* __restrict__ cursor) {
    int i = blockIdx.x * blockDim.x + threadIdx.x;
    if (i < N_NODES) cursor[i] = rowptr[i];
}

__global__ void scatter_kernel(const int* __restrict__ edge, int* __restrict__ cursor,
                               int* __restrict__ csr) {
    int e = blockIdx.x * blockDim.x + threadIdx.x;
    if (e < N_EDGES) {
        int d = edge[N_EDGES + e];
        int p = atomicAdd(&cursor[d], 1);
        csr[p] = edge[e];
    }
}

// ---------------- edge aggregation (pull, no float atomics) ----------------
// 256-thread blocks; each wave-sized group of F threads owns one node.

template <int F>
__global__ void aggregate_kernel(const float* __restrict__ X, const int* __restrict__ rowptr,
                                 const int* __restrict__ csr, float* __restrict__ OUT) {
    constexpr int NPB = 256 / F;
    int i = blockIdx.x * NPB + threadIdx.x / F;  // node
    int f = threadIdx.x % F;                     // feature
    if (i >= N_NODES) return;
    int s = rowptr[i], e = rowptr[i + 1];
    float acc = 0.f;
    for (int p = s; p < e; ++p) {
        int j = csr[p];
        acc += X[(size_t)j * F + f];
    }
    OUT[(size_t)i * F + f] = acc;
}

// ---------------- fused node GEMM ----------------
// OUT[i][o] = act( sum_k A1[i,k]*W1[o,k] (+ sum_k A2[i,k]*W2[o,k]) (+ ADDIN[i,o]) (+ bias[o]) )
template <int K, int N, bool TWO, bool RELU, bool HASADD, bool HASBIAS>
__launch_bounds__(256)
__global__ void gemm_fused(const float* __restrict__ A1, const float* __restrict__ W1,
                           const float* __restrict__ A2, const float* __restrict__ W2,
                           const float* __restrict__ bias, const float* __restrict__ ADDIN,
                           float* __restrict__ OUT, int M) {
    constexpr int BM = 64, KC = 32, TM = 4, TN = N / 16;
    __shared__ float A1t[KC][BM];
    __shared__ float A2t[TWO ? KC : 1][TWO ? BM : 1];
    __shared__ float W1c[KC][N];
    __shared__ float W2c[TWO ? KC : 1][TWO ? N : 1];

    int tid = threadIdx.x;
    int colt = tid & 15, rowt = tid >> 4;
    int i0 = blockIdx.x * BM;

    float acc[TM][TN];
#pragma unroll
    for (int m = 0; m < TM; ++m)
#pragma unroll
        for (int n = 0; n < TN; ++n) acc[m][n] = 0.f;

    for (int c0 = 0; c0 < K; c0 += KC) {
        // stage A tile(s), transposed: A1t[k][row]
#pragma unroll
        for (int j = 0; j < (BM * KC / 4) / 256; ++j) {  // 2 iters
            int lin = tid + j * 256;
            int row = lin >> 3, k4 = (lin & 7) * 4;
            int gr = i0 + row;
            float4 v = f4zero();
            if (gr < M) v = *(const float4*)(A1 + (size_t)gr * K + c0 + k4);
            A1t[k4 + 0][row] = v.x; A1t[k4 + 1][row] = v.y;
            A1t[k4 + 2][row] = v.z; A1t[k4 + 3][row] = v.w;
            if constexpr (TWO) {
                float4 u = f4zero();
                if (gr < M) u = *(const float4*)(A2 + (size_t)gr * K + c0 + k4);
                A2t[k4 + 0][row] = u.x; A2t[k4 + 1][row] = u.y;
                A2t[k4 + 2][row] = u.z; A2t[k4 + 3][row] = u.w;
            }
        }
        // stage W chunk(s): W1c[k][o]
#pragma unroll
        for (int j = 0; j < (KC * N / 4) / 256; ++j) {
            int lin = tid + j * 256;
            int o = lin >> 3, k4 = (lin & 7) * 4;
            float4 v = *(const float4*)(W1 + (size_t)o * K + c0 + k4);
            W1c[k4 + 0][o] = v.x; W1c[k4 + 1][o] = v.y;
            W1c[k4 + 2][o] = v.z; W1c[k4 + 3][o] = v.w;
            if constexpr (TWO) {
                float4 u = *(const float4*)(W2 + (size_t)o * K + c0 + k4);
                W2c[k4 + 0][o] = u.x; W2c[k4 + 1][o] = u.y;
                W2c[k4 + 2][o] = u.z; W2c[k4 + 3][o] = u.w;
            }
        }
        __syncthreads();
#pragma unroll
        for (int k = 0; k < KC; ++k) {
            float a1[TM];
            *(float4*)a1 = *(const float4*)&A1t[k][rowt * TM];
            float w1[TN];
#pragma unroll
            for (int n4 = 0; n4 < TN; n4 += 4)
                *(float4*)&w1[n4] = *(const float4*)&W1c[k][colt * TN + n4];
#pragma unroll
            for (int m = 0; m < TM; ++m)
#pragma unroll
                for (int n = 0; n < TN; ++n) acc[m][n] += a1[m] * w1[n];
            if constexpr (TWO) {
                float a2[TM];
                *(float4*)a2 = *(const float4*)&A2t[k][rowt * TM];
                float w2[TN];
#pragma unroll
                for (int n4 = 0; n4 < TN; n4 += 4)
                    *(float4*)&w2[n4] = *(const float4*)&W2c[k][colt * TN + n4];
#pragma unroll
                for (int m = 0; m < TM; ++m)
#pragma unroll
                    for (int n = 0; n < TN; ++n) acc[m][n] += a2[m] * w2[n];
            }
        }
        __syncthreads();
    }
    // epilogue
#pragma unroll
    for (int m = 0; m < TM; ++m) {
        int gr = i0 + rowt * TM + m;
        if (gr >= M) continue;
#pragma unroll
        for (int n4 = 0; n4 < TN; n4 += 4) {
            int col = colt * TN + n4;
            float4 v = make_float4(acc[m][n4], acc[m][n4 + 1], acc[m][n4 + 2], acc[m][n4 + 3]);
            if constexpr (HASBIAS) {
                float4 b = *(const float4*)(bias + col);
                v.x += b.x; v.y += b.y; v.z += b.z; v.w += b.w;
            }
            if constexpr (HASADD) {
                float4 a = *(const float4*)(ADDIN + (size_t)gr * N + col);
                v.x += a.x; v.y += a.y; v.z += a.z; v.w += a.w;
            }
            if constexpr (RELU) {
                v.x = fmaxf(v.x, 0.f); v.y = fmaxf(v.y, 0.f);
                v.z = fmaxf(v.z, 0.f); v.w = fmaxf(v.w, 0.f);
            }
            *(float4*)(OUT + (size_t)gr * N + col) = v;
        }
    }
}

// ---------------- pooling (batch is sorted) ----------------

__global__ void pool_kernel(const float* __restrict__ H, const int* __restrict__ batch,
                            float* __restrict__ G, int n) {
    const int CHUNK = 128;
    int f = threadIdx.x;  // 64 threads
    int start = blockIdx.x * CHUNK;
    if (start >= n) return;
    int end = start + CHUNK; if (end > n) end = n;
    int cur = batch[start];
    float acc = 0.f;
    for (int i = start; i < end; ++i) {
        int b = batch[i];
        if (b != cur) { atomicAdd(&G[(size_t)cur * 64 + f], acc); acc = 0.f; cur = b; }
        acc += H[(size_t)i * 64 + f];
    }
    atomicAdd(&G[(size_t)cur * 64 + f], acc);
}

// ---------------- MLP head + log_softmax ----------------

__global__ void mlp_head(const float* __restrict__ G, const float* __restrict__ fc1w,
                         const float* __restrict__ fc1b, const float* __restrict__ fc2w,
                         const float* __restrict__ fc2b, float* __restrict__ out) {
    int g = blockIdx.x;
    int t = threadIdx.x;  // 64
    __shared__ float gr[64], tt[64], sc[32], red[2];
    gr[t] = G[(size_t)g * 64 + t];
    __syncthreads();
    float acc = fc1b[t];
#pragma unroll
    for (int k = 0; k < 64; ++k) acc += gr[k] * fc1w[t * 64 + k];
    tt[t] = fmaxf(acc, 0.f);
    __syncthreads();
    if (t < 32) {
        float s = fc2b[t];
#pragma unroll
        for (int k = 0; k < 64; ++k) s += tt[k] * fc2w[t * 64 + k];
        sc[t] = s;
    }
    __syncthreads();
    if (t == 0) {
        float mx = sc[0];
        for (int c = 1; c < 32; ++c) mx = fmaxf(mx, sc[c]);
        float sum = 0.f;
        for (int c = 0; c < 32; ++c) sum += expf(sc[c] - mx);
        red[0] = mx; red[1] = logf(sum);
    }
    __syncthreads();
    if (t < 32) out[(size_t)g * 32 + t] = sc[t] - red[0] - red[1];
}

// ---------------- launch ----------------

extern "C" void kernel_launch(void* const* d_in, const int* in_sizes, int n_in,
                              void* d_out, int out_size, void* d_ws, size_t ws_size,
                              hipStream_t stream) {
    const float* x       = (const float*)d_in[0];
    const int*   edge    = (const int*)d_in[1];   // [2][E]: row0=src, row1=dst
    const int*   batch   = (const int*)d_in[2];
    const float* w1_rel  = (const float*)d_in[3];
    const float* b1      = (const float*)d_in[4];
    const float* w1_root = (const float*)d_in[5];
    const float* w2_rel  = (const float*)d_in[6];
    const float* b2      = (const float*)d_in[7];
    const float* w2_root = (const float*)d_in[8];
    const float* w3_rel  = (const float*)d_in[9];
    const float* b3      = (const float*)d_in[10];
    const float* w3_root = (const float*)d_in[11];
    const float* fc1w    = (const float*)d_in[12];
    const float* fc1b    = (const float*)d_in[13];
    const float* fc2w    = (const float*)d_in[14];
    const float* fc2b    = (const float*)d_in[15];
    float* out = (float*)d_out;

    char* p = (char*)d_ws;
    size_t used = 0;
    auto alloc = [&](size_t bytes) {
        char* r = p + used;
        used += (bytes + 255) & ~(size_t)255;
        return r;
    };
    int*   rowptr = (int*)alloc((N_NODES + 1) * sizeof(int));
    int*   cursor = (int*)alloc(N_NODES * sizeof(int));
    int*   csr    = (int*)alloc(N_EDGES * sizeof(int));
    int*   bsum   = (int*)alloc(SCAN_NB * sizeof(int));
    // Two big 25.6MB regions; 64-wide temporaries alias into them once the
    // 128-wide tenants are dead.  Peak d_ws use ≈ 54 MB.
    float* A      = (float*)alloc((size_t)N_NODES * 128 * sizeof(float));  // aggr1; later C|D
    float* B      = (float*)alloc((size_t)N_NODES * 128 * sizeof(float));  // h1;    later E
    float* G      = (float*)alloc((size_t)N_GRAPHS * 64 * sizeof(float));

    // Workspace guard: if the harness gave us less scratch than needed, bail
    // out cleanly (wrong answer, but no wild device writes / container death).
    if (used > ws_size) return;

    float* C = A;                         // [N,64]  y2 / h2
    float* D = A + (size_t)N_NODES * 64;  // [N,64]  aggr2 / y3 / h3
    float* E = B;                         // [N,64]  aggr3 (h1 dead by then)

    // CSR build (shared by all 3 layers)
    zero_int_kernel<<<(N_NODES + 256) / 256, 256, 0, stream>>>(rowptr, N_NODES + 1);
    hist_kernel<<<(N_EDGES + 255) / 256, 256, 0, stream>>>(edge, rowptr);
    scan_reduce_kernel<<<SCAN_NB, 256, 0, stream>>>(rowptr, bsum);
    scan_sums_kernel<<<1, 64, 0, stream>>>(bsum);
    scan_apply_kernel<<<SCAN_NB, 256, 0, stream>>>(rowptr, bsum);
    cursor_kernel<<<(N_NODES + 255) / 256, 256, 0, stream>>>(rowptr, cursor);
    scatter_kernel<<<(N_EDGES + 255) / 256, 256, 0, stream>>>(edge, cursor, csr);

    int gblk = (N_NODES + 63) / 64;

    // Layer 1: aggr1 = segsum(x); h1 = relu(aggr1@w1_rel.T + x@w1_root.T + b1)
    aggregate_kernel<128><<<(N_NODES + 1) / 2, 256, 0, stream>>>(x, rowptr, csr, A);
    gemm_fused<128, 128, true, true, false, true>
        <<<gblk, 256, 0, stream>>>(A, w1_rel, x, w1_root, b1, nullptr, B, N_NODES);

    // Layer 2 (transform-first): y2 = h1@w2_rel.T; aggr2 = segsum(y2);
    // h2 = relu(aggr2 + h1@w2_root.T + b2)
    gemm_fused<128, 64, false, false, false, false>
        <<<gblk, 256, 0, stream>>>(B, w2_rel, nullptr, nullptr, nullptr, nullptr, C, N_NODES);
    aggregate_kernel<64><<<(N_NODES + 3) / 4, 256, 0, stream>>>(C, rowptr, csr, D);
    gemm_fused<128, 64, false, true, true, true>
        <<<gblk, 256, 0, stream>>>(B, w2_root, nullptr, nullptr, b2, D, C, N_NODES);

    // Layer 3: y3 = h2@w3_rel.T; aggr3 = segsum(y3); h3 = aggr3 + h2@w3_root.T + b3
    gemm_fused<64, 64, false, false, false, false>
        <<<gblk, 256, 0, stream>>>(C, w3_rel, nullptr, nullptr, nullptr, nullptr, D, N_NODES);
    aggregate_kernel<64><<<(N_NODES + 3) / 4, 256, 0, stream>>>(D, rowptr, csr, E);
    gemm_fused<64, 64, false, false, true, true>
        <<<gblk, 256, 0, stream>>>(C, w3_root, nullptr, nullptr, b3, E, D, N_NODES);

    // Pool + head
    zero_float_kernel<<<(N_GRAPHS * 64 + 255) / 256, 256, 0, stream>>>(G, N_GRAPHS * 64);
    pool_kernel<<<(N_NODES + 127) / 128, 64, 0, stream>>>(D, batch, G, N_NODES);
    mlp_head<<<N_GRAPHS, 64, 0, stream>>>(G, fc1w, fc1b, fc2w, fc2b, out);
}

// Round 8
// 444.527 us; speedup vs baseline: 1.3095x; 1.3095x over previous
//
#include <hip/hip_runtime.h>

#define N_NODES  50000
#define N_EDGES  600000
#define N_GRAPHS 512

#define SCAN_N   (N_NODES + 1)
#define SCAN_BPB 1024                                   // elements per scan block
#define SCAN_NB  ((SCAN_N + SCAN_BPB - 1) / SCAN_BPB)   // 49

static __device__ __forceinline__ float4 f4zero() { return make_float4(0.f, 0.f, 0.f, 0.f); }

// ---------------- tiny init kernels (avoid hipMemsetAsync under capture) ----

__global__ void zero_int_kernel(int* __restrict__ p, int n) {
    int i = blockIdx.x * blockDim.x + threadIdx.x;
    if (i < n) p[i] = 0;
}
__global__ void zero_float_kernel(float* __restrict__ p, int n) {
    int i = blockIdx.x * blockDim.x + threadIdx.x;
    if (i < n) p[i] = 0.f;
}

// ---------------- CSR build ----------------

__global__ void hist_kernel(const int* __restrict__ edge, int* __restrict__ rowptr) {
    int e = blockIdx.x * blockDim.x + threadIdx.x;
    if (e < N_EDGES) atomicAdd(&rowptr[edge[N_EDGES + e] + 1], 1);
}

// --- hierarchical 3-pass inclusive scan over data[0..SCAN_N-1] -------------
__global__ void scan_reduce_kernel(const int* __restrict__ data, int* __restrict__ bsum) {
    __shared__ int red[256];
    int b = blockIdx.x, t = threadIdx.x;
    int base = b * SCAN_BPB + t * 4;
    int s = 0;
#pragma unroll
    for (int j = 0; j < 4; ++j) {
        int idx = base + j;
        if (idx < SCAN_N) s += data[idx];
    }
    red[t] = s;
    __syncthreads();
    for (int off = 128; off > 0; off >>= 1) {
        if (t < off) red[t] += red[t + off];
        __syncthreads();
    }
    if (t == 0) bsum[b] = red[0];
}

__global__ void scan_sums_kernel(int* __restrict__ bsum) {
    __shared__ int sh[SCAN_NB];
    int t = threadIdx.x;
    if (t < SCAN_NB) sh[t] = bsum[t];
    __syncthreads();
    if (t == 0) {
        int run = 0;
        for (int i = 0; i < SCAN_NB; ++i) { int v = sh[i]; sh[i] = run; run += v; }
    }
    __syncthreads();
    if (t < SCAN_NB) bsum[t] = sh[t];
}

__global__ void scan_apply_kernel(int* __restrict__ data, const int* __restrict__ bexc) {
    __shared__ int th[256];
    int b = blockIdx.x, t = threadIdx.x;
    int base = b * SCAN_BPB + t * 4;
    int v[4];
    int s = 0;
#pragma unroll
    for (int j = 0; j < 4; ++j) {
        int idx = base + j;
        v[j] = (idx < SCAN_N) ? data[idx] : 0;
        s += v[j];
    }
    th[t] = s;
    __syncthreads();
    for (int off = 1; off < 256; off <<= 1) {
        int x = (t >= off) ? th[t - off] : 0;
        __syncthreads();
        th[t] += x;
        __syncthreads();
    }
    int run = bexc[b] + th[t] - s;
#pragma unroll
    for (int j = 0; j < 4; ++j) {
        int idx = base + j;
        run += v[j];
        if (idx < SCAN_N) data[idx] = run;
    }
}

__global__ void cursor_kernel(const int* __restrict__ rowptr, int* __restrict__ cursor) {
    int i = blockIdx.x * blockDim.x + threadIdx.x;
    if (i < N_NODES) cursor[i] = rowptr[i];
}

__global__ void scatter_kernel(const int* __restrict__ edge, int* __restrict__ cursor,
                               int* __restrict__ csr) {
    int e = blockIdx.x * blockDim.x + threadIdx.x;
    if (e < N_EDGES) {
        int d = edge[N_EDGES + e];
        int p = atomicAdd(&cursor[d], 1);
        csr[p] = edge[e];
    }
}

// ---------------- edge aggregation v2: float2 lanes + 4-deep ILP -----------
// F2 = F/2 float2 elements per row.  LPN lanes own one node; lane l holds
// features [2l, 2l+2).  4 independent gathers in flight per chunk.

template <int F2, int LPN>
__global__ void aggregate_v2(const float* __restrict__ X, const int* __restrict__ rowptr,
                             const int* __restrict__ csr, float* __restrict__ OUT) {
    constexpr int NPB = 256 / LPN;  // nodes per block
    int grp  = threadIdx.x / LPN;
    int lane = threadIdx.x % LPN;
    int i = blockIdx.x * NPB + grp;
    if (i >= N_NODES) return;
    const float2* __restrict__ X2 = (const float2*)X;
    int s = rowptr[i], e = rowptr[i + 1];
    float ax = 0.f, ay = 0.f, bx = 0.f, by = 0.f;
    int p = s;
    for (; p + 4 <= e; p += 4) {
        int j0 = csr[p + 0], j1 = csr[p + 1], j2 = csr[p + 2], j3 = csr[p + 3];
        float2 v0 = X2[(size_t)j0 * F2 + lane];
        float2 v1 = X2[(size_t)j1 * F2 + lane];
        float2 v2 = X2[(size_t)j2 * F2 + lane];
        float2 v3 = X2[(size_t)j3 * F2 + lane];
        ax += v0.x + v1.x; ay += v0.y + v1.y;
        bx += v2.x + v3.x; by += v2.y + v3.y;
    }
    if (p + 2 <= e) {
        int j0 = csr[p], j1 = csr[p + 1];
        float2 v0 = X2[(size_t)j0 * F2 + lane];
        float2 v1 = X2[(size_t)j1 * F2 + lane];
        ax += v0.x + v1.x; ay += v0.y + v1.y;
        p += 2;
    }
    if (p < e) {
        float2 v = X2[(size_t)csr[p] * F2 + lane];
        bx += v.x; by += v.y;
    }
    float2 r; r.x = ax + bx; r.y = ay + by;
    ((float2*)OUT)[(size_t)i * F2 + lane] = r;
}

// ---------------- fused node GEMM ----------------
// OUT[i][o] = act( sum_k A1[i,k]*W1[o,k] (+ sum_k A2[i,k]*W2[o,k]) (+ ADDIN[i,o]) (+ bias[o]) )
template <int K, int N, bool TWO, bool RELU, bool HASADD, bool HASBIAS>
__launch_bounds__(256)
__global__ void gemm_fused(const float* __restrict__ A1, const float* __restrict__ W1,
                           const float* __restrict__ A2, const float* __restrict__ W2,
                           const float* __restrict__ bias, const float* __restrict__ ADDIN,
                           float* __restrict__ OUT, int M) {
    constexpr int BM = 64, KC = 32, TM = 4, TN = N / 16;
    __shared__ float A1t[KC][BM];
    __shared__ float A2t[TWO ? KC : 1][TWO ? BM : 1];
    __shared__ float W1c[KC][N];
    __shared__ float W2c[TWO ? KC : 1][TWO ? N : 1];

    int tid = threadIdx.x;
    int colt = tid & 15, rowt = tid >> 4;
    int i0 = blockIdx.x * BM;

    float acc[TM][TN];
#pragma unroll
    for (int m = 0; m < TM; ++m)
#pragma unroll
        for (int n = 0; n < TN; ++n) acc[m][n] = 0.f;

    for (int c0 = 0; c0 < K; c0 += KC) {
#pragma unroll
        for (int j = 0; j < (BM * KC / 4) / 256; ++j) {
            int lin = tid + j * 256;
            int row = lin >> 3, k4 = (lin & 7) * 4;
            int gr = i0 + row;
            float4 v = f4zero();
            if (gr < M) v = *(const float4*)(A1 + (size_t)gr * K + c0 + k4);
            A1t[k4 + 0][row] = v.x; A1t[k4 + 1][row] = v.y;
            A1t[k4 + 2][row] = v.z; A1t[k4 + 3][row] = v.w;
            if constexpr (TWO) {
                float4 u = f4zero();
                if (gr < M) u = *(const float4*)(A2 + (size_t)gr * K + c0 + k4);
                A2t[k4 + 0][row] = u.x; A2t[k4 + 1][row] = u.y;
                A2t[k4 + 2][row] = u.z; A2t[k4 + 3][row] = u.w;
            }
        }
#pragma unroll
        for (int j = 0; j < (KC * N / 4) / 256; ++j) {
            int lin = tid + j * 256;
            int o = lin >> 3, k4 = (lin & 7) * 4;
            float4 v = *(const float4*)(W1 + (size_t)o * K + c0 + k4);
            W1c[k4 + 0][o] = v.x; W1c[k4 + 1][o] = v.y;
            W1c[k4 + 2][o] = v.z; W1c[k4 + 3][o] = v.w;
            if constexpr (TWO) {
                float4 u = *(const float4*)(W2 + (size_t)o * K + c0 + k4);
                W2c[k4 + 0][o] = u.x; W2c[k4 + 1][o] = u.y;
                W2c[k4 + 2][o] = u.z; W2c[k4 + 3][o] = u.w;
            }
        }
        __syncthreads();
#pragma unroll
        for (int k = 0; k < KC; ++k) {
            float a1[TM];
            *(float4*)a1 = *(const float4*)&A1t[k][rowt * TM];
            float w1[TN];
#pragma unroll
            for (int n4 = 0; n4 < TN; n4 += 4)
                *(float4*)&w1[n4] = *(const float4*)&W1c[k][colt * TN + n4];
#pragma unroll
            for (int m = 0; m < TM; ++m)
#pragma unroll
                for (int n = 0; n < TN; ++n) acc[m][n] += a1[m] * w1[n];
            if constexpr (TWO) {
                float a2[TM];
                *(float4*)a2 = *(const float4*)&A2t[k][rowt * TM];
                float w2[TN];
#pragma unroll
                for (int n4 = 0; n4 < TN; n4 += 4)
                    *(float4*)&w2[n4] = *(const float4*)&W2c[k][colt * TN + n4];
#pragma unroll
                for (int m = 0; m < TM; ++m)
#pragma unroll
                    for (int n = 0; n < TN; ++n) acc[m][n] += a2[m] * w2[n];
            }
        }
        __syncthreads();
    }
#pragma unroll
    for (int m = 0; m < TM; ++m) {
        int gr = i0 + rowt * TM + m;
        if (gr >= M) continue;
#pragma unroll
        for (int n4 = 0; n4 < TN; n4 += 4) {
            int col = colt * TN + n4;
            float4 v = make_float4(acc[m][n4], acc[m][n4 + 1], acc[m][n4 + 2], acc[m][n4 + 3]);
            if constexpr (HASBIAS) {
                float4 b = *(const float4*)(bias + col);
                v.x += b.x; v.y += b.y; v.z += b.z; v.w += b.w;
            }
            if constexpr (HASADD) {
                float4 a = *(const float4*)(ADDIN + (size_t)gr * N + col);
                v.x += a.x; v.y += a.y; v.z += a.z; v.w += a.w;
            }
            if constexpr (RELU) {
                v.x = fmaxf(v.x, 0.f); v.y = fmaxf(v.y, 0.f);
                v.z = fmaxf(v.z, 0.f); v.w = fmaxf(v.w, 0.f);
            }
            *(float4*)(OUT + (size_t)gr * N + col) = v;
        }
    }
}

// ---------------- pooling (batch is sorted) ----------------

__global__ void pool_kernel(const float* __restrict__ H, const int* __restrict__ batch,
                            float* __restrict__ G, int n) {
    const int CHUNK = 128;
    int f = threadIdx.x;  // 64 threads
    int start = blockIdx.x * CHUNK;
    if (start >= n) return;
    int end = start + CHUNK; if (end > n) end = n;
    int cur = batch[start];
    float acc = 0.f;
    for (int i = start; i < end; ++i) {
        int b = batch[i];
        if (b != cur) { atomicAdd(&G[(size_t)cur * 64 + f], acc); acc = 0.f; cur = b; }
        acc += H[(size_t)i * 64 + f];
    }
    atomicAdd(&G[(size_t)cur * 64 + f], acc);
}

// ---------------- MLP head + log_softmax ----------------

__global__ void mlp_head(const float* __restrict__ G, const float* __restrict__ fc1w,
                         const float* __restrict__ fc1b, const float* __restrict__ fc2w,
                         const float* __restrict__ fc2b, float* __restrict__ out) {
    int g = blockIdx.x;
    int t = threadIdx.x;  // 64
    __shared__ float gr[64], tt[64], sc[32], red[2];
    gr[t] = G[(size_t)g * 64 + t];
    __syncthreads();
    float acc = fc1b[t];
#pragma unroll
    for (int k = 0; k < 64; ++k) acc += gr[k] * fc1w[t * 64 + k];
    tt[t] = fmaxf(acc, 0.f);
    __syncthreads();
    if (t < 32) {
        float s = fc2b[t];
#pragma unroll
        for (int k = 0; k < 64; ++k) s += tt[k] * fc2w[t * 64 + k];
        sc[t] = s;
    }
    __syncthreads();
    if (t == 0) {
        float mx = sc[0];
        for (int c = 1; c < 32; ++c) mx = fmaxf(mx, sc[c]);
        float sum = 0.f;
        for (int c = 0; c < 32; ++c) sum += expf(sc[c] - mx);
        red[0] = mx; red[1] = logf(sum);
    }
    __syncthreads();
    if (t < 32) out[(size_t)g * 32 + t] = sc[t] - red[0] - red[1];
}

// ---------------- launch ----------------

extern "C" void kernel_launch(void* const* d_in, const int* in_sizes, int n_in,
                              void* d_out, int out_size, void* d_ws, size_t ws_size,
                              hipStream_t stream) {
    const float* x       = (const float*)d_in[0];
    const int*   edge    = (const int*)d_in[1];   // [2][E]: row0=src, row1=dst
    const int*   batch   = (const int*)d_in[2];
    const float* w1_rel  = (const float*)d_in[3];
    const float* b1      = (const float*)d_in[4];
    const float* w1_root = (const float*)d_in[5];
    const float* w2_rel  = (const float*)d_in[6];
    const float* b2      = (const float*)d_in[7];
    const float* w2_root = (const float*)d_in[8];
    const float* w3_rel  = (const float*)d_in[9];
    const float* b3      = (const float*)d_in[10];
    const float* w3_root = (const float*)d_in[11];
    const float* fc1w    = (const float*)d_in[12];
    const float* fc1b    = (const float*)d_in[13];
    const float* fc2w    = (const float*)d_in[14];
    const float* fc2b    = (const float*)d_in[15];
    float* out = (float*)d_out;

    char* p = (char*)d_ws;
    size_t used = 0;
    auto alloc = [&](size_t bytes) {
        char* r = p + used;
        used += (bytes + 255) & ~(size_t)255;
        return r;
    };
    int*   rowptr = (int*)alloc((N_NODES + 1) * sizeof(int));
    int*   cursor = (int*)alloc(N_NODES * sizeof(int));
    int*   csr    = (int*)alloc(N_EDGES * sizeof(int));
    int*   bsum   = (int*)alloc(SCAN_NB * sizeof(int));
    float* A      = (float*)alloc((size_t)N_NODES * 128 * sizeof(float));  // aggr1; later C|D
    float* B      = (float*)alloc((size_t)N_NODES * 128 * sizeof(float));  // h1;    later E
    float* G      = (float*)alloc((size_t)N_GRAPHS * 64 * sizeof(float));

    if (used > ws_size) return;  // clean bail instead of wild writes

    float* C = A;                         // [N,64]  y2 / h2
    float* D = A + (size_t)N_NODES * 64;  // [N,64]  aggr2 / y3 / h3
    float* E = B;                         // [N,64]  aggr3 (h1 dead by then)

    // CSR build (shared by all 3 layers)
    zero_int_kernel<<<(N_NODES + 256) / 256, 256, 0, stream>>>(rowptr, N_NODES + 1);
    hist_kernel<<<(N_EDGES + 255) / 256, 256, 0, stream>>>(edge, rowptr);
    scan_reduce_kernel<<<SCAN_NB, 256, 0, stream>>>(rowptr, bsum);
    scan_sums_kernel<<<1, 64, 0, stream>>>(bsum);
    scan_apply_kernel<<<SCAN_NB, 256, 0, stream>>>(rowptr, bsum);
    cursor_kernel<<<(N_NODES + 255) / 256, 256, 0, stream>>>(rowptr, cursor);
    scatter_kernel<<<(N_EDGES + 255) / 256, 256, 0, stream>>>(edge, cursor, csr);

    int gblk = (N_NODES + 63) / 64;

    // Layer 1: aggr1 = segsum(x); h1 = relu(aggr1@w1_rel.T + x@w1_root.T + b1)
    aggregate_v2<64, 64><<<(N_NODES + 3) / 4, 256, 0, stream>>>(x, rowptr, csr, A);
    gemm_fused<128, 128, true, true, false, true>
        <<<gblk, 256, 0, stream>>>(A, w1_rel, x, w1_root, b1, nullptr, B, N_NODES);

    // Layer 2 (transform-first): y2 = h1@w2_rel.T; aggr2 = segsum(y2);
    // h2 = relu(aggr2 + h1@w2_root.T + b2)
    gemm_fused<128, 64, false, false, false, false>
        <<<gblk, 256, 0, stream>>>(B, w2_rel, nullptr, nullptr, nullptr, nullptr, C, N_NODES);
    aggregate_v2<32, 32><<<(N_NODES + 7) / 8, 256, 0, stream>>>(C, rowptr, csr, D);
    gemm_fused<128, 64, false, true, true, true>
        <<<gblk, 256, 0, stream>>>(B, w2_root, nullptr, nullptr, b2, D, C, N_NODES);

    // Layer 3: y3 = h2@w3_rel.T; aggr3 = segsum(y3); h3 = aggr3 + h2@w3_root.T + b3
    gemm_fused<64, 64, false, false, false, false>
        <<<gblk, 256, 0, stream>>>(C, w3_rel, nullptr, nullptr, nullptr, nullptr, D, N_NODES);
    aggregate_v2<32, 32><<<(N_NODES + 7) / 8, 256, 0, stream>>>(D, rowptr, csr, E);
    gemm_fused<64, 64, false, false, true, true>
        <<<gblk, 256, 0, stream>>>(C, w3_root, nullptr, nullptr, b3, E, D, N_NODES);

    // Pool + head
    zero_float_kernel<<<(N_GRAPHS * 64 + 255) / 256, 256, 0, stream>>>(G, N_GRAPHS * 64);
    pool_kernel<<<(N_NODES + 127) / 128, 64, 0, stream>>>(D, batch, G, N_NODES);
    mlp_head<<<N_GRAPHS, 64, 0, stream>>>(G, fc1w, fc1b, fc2w, fc2b, out);
}

// Round 9
// 426.440 us; speedup vs baseline: 1.3650x; 1.0424x over previous
//
#include <hip/hip_runtime.h>

#define N_NODES  50000
#define N_EDGES  600000
#define N_GRAPHS 512

#define SCAN_N   (N_NODES + 1)
#define SCAN_BPB 1024                                   // elements per scan block
#define SCAN_NB  ((SCAN_N + SCAN_BPB - 1) / SCAN_BPB)   // 49

static __device__ __forceinline__ float4 f4zero() { return make_float4(0.f, 0.f, 0.f, 0.f); }

// ---------------- tiny init kernels (avoid hipMemsetAsync under capture) ----

__global__ void zero_int_kernel(int* __restrict__ p, int n) {
    int i = blockIdx.x * blockDim.x + threadIdx.x;
    if (i < n) p[i] = 0;
}
__global__ void zero_float_kernel(float* __restrict__ p, int n) {
    int i = blockIdx.x * blockDim.x + threadIdx.x;
    if (i < n) p[i] = 0.f;
}

// ---------------- CSR build ----------------

__global__ void hist_kernel(const int* __restrict__ edge, int* __restrict__ rowptr) {
    int e = blockIdx.x * blockDim.x + threadIdx.x;
    if (e < N_EDGES) atomicAdd(&rowptr[edge[N_EDGES + e] + 1], 1);
}

// --- hierarchical 3-pass inclusive scan over data[0..SCAN_N-1] -------------
__global__ void scan_reduce_kernel(const int* __restrict__ data, int* __restrict__ bsum) {
    __shared__ int red[256];
    int b = blockIdx.x, t = threadIdx.x;
    int base = b * SCAN_BPB + t * 4;
    int s = 0;
#pragma unroll
    for (int j = 0; j < 4; ++j) {
        int idx = base + j;
        if (idx < SCAN_N) s += data[idx];
    }
    red[t] = s;
    __syncthreads();
    for (int off = 128; off > 0; off >>= 1) {
        if (t < off) red[t] += red[t + off];
        __syncthreads();
    }
    if (t == 0) bsum[b] = red[0];
}

__global__ void scan_sums_kernel(int* __restrict__ bsum) {
    __shared__ int sh[SCAN_NB];
    int t = threadIdx.x;
    if (t < SCAN_NB) sh[t] = bsum[t];
    __syncthreads();
    if (t == 0) {
        int run = 0;
        for (int i = 0; i < SCAN_NB; ++i) { int v = sh[i]; sh[i] = run; run += v; }
    }
    __syncthreads();
    if (t < SCAN_NB) bsum[t] = sh[t];
}

__global__ void scan_apply_kernel(int* __restrict__ data, const int* __restrict__ bexc) {
    __shared__ int th[256];
    int b = blockIdx.x, t = threadIdx.x;
    int base = b * SCAN_BPB + t * 4;
    int v[4];
    int s = 0;
#pragma unroll
    for (int j = 0; j < 4; ++j) {
        int idx = base + j;
        v[j] = (idx < SCAN_N) ? data[idx] : 0;
        s += v[j];
    }
    th[t] = s;
    __syncthreads();
    for (int off = 1; off < 256; off <<= 1) {
        int x = (t >= off) ? th[t - off] : 0;
        __syncthreads();
        th[t] += x;
        __syncthreads();
    }
    int run = bexc[b] + th[t] - s;
#pragma unroll
    for (int j = 0; j < 4; ++j) {
        int idx = base + j;
        run += v[j];
        if (idx < SCAN_N) data[idx] = run;
    }
}

__global__ void cursor_kernel(const int* __restrict__ rowptr, int* __restrict__ cursor) {
    int i = blockIdx.x * blockDim.x + threadIdx.x;
    if (i < N_NODES) cursor[i] = rowptr[i];
}

__global__ void scatter_kernel(const int* __restrict__ edge, int* __restrict__ cursor,
                               int* __restrict__ csr) {
    int e = blockIdx.x * blockDim.x + threadIdx.x;
    if (e < N_EDGES) {
        int d = edge[N_EDGES + e];
        int p = atomicAdd(&cursor[d], 1);
        csr[p] = edge[e];
    }
}

// ---------------- edge aggregation v2: float2 lanes + 4-deep ILP -----------

template <int F2, int LPN>
__global__ void aggregate_v2(const float* __restrict__ X, const int* __restrict__ rowptr,
                             const int* __restrict__ csr, float* __restrict__ OUT) {
    constexpr int NPB = 256 / LPN;  // nodes per block
    int grp  = threadIdx.x / LPN;
    int lane = threadIdx.x % LPN;
    int i = blockIdx.x * NPB + grp;
    if (i >= N_NODES) return;
    const float2* __restrict__ X2 = (const float2*)X;
    int s = rowptr[i], e = rowptr[i + 1];
    float ax = 0.f, ay = 0.f, bx = 0.f, by = 0.f;
    int p = s;
    for (; p + 4 <= e; p += 4) {
        int j0 = csr[p + 0], j1 = csr[p + 1], j2 = csr[p + 2], j3 = csr[p + 3];
        float2 v0 = X2[(size_t)j0 * F2 + lane];
        float2 v1 = X2[(size_t)j1 * F2 + lane];
        float2 v2 = X2[(size_t)j2 * F2 + lane];
        float2 v3 = X2[(size_t)j3 * F2 + lane];
        ax += v0.x + v1.x; ay += v0.y + v1.y;
        bx += v2.x + v3.x; by += v2.y + v3.y;
    }
    if (p + 2 <= e) {
        int j0 = csr[p], j1 = csr[p + 1];
        float2 v0 = X2[(size_t)j0 * F2 + lane];
        float2 v1 = X2[(size_t)j1 * F2 + lane];
        ax += v0.x + v1.x; ay += v0.y + v1.y;
        p += 2;
    }
    if (p < e) {
        float2 v = X2[(size_t)csr[p] * F2 + lane];
        bx += v.x; by += v.y;
    }
    float2 r; r.x = ax + bx; r.y = ay + by;
    ((float2*)OUT)[(size_t)i * F2 + lane] = r;
}

// ---------------- fused node GEMM v2 ----------------
// BM=128, KC=16, TM=8; +4-float LDS row padding kills the 8-way staging
// write conflicts (bank = (4k+row)%32 -> 2-way, free per m136).
// OUT[i][o] = act( A1[i,:]@W1[o,:] (+ A2[i,:]@W2[o,:]) (+ ADDIN[i,o]) (+ bias[o]) )
template <int K, int N, bool TWO, bool RELU, bool HASADD, bool HASBIAS>
__launch_bounds__(256, 2)
__global__ void gemm_v2(const float* __restrict__ A1, const float* __restrict__ W1,
                        const float* __restrict__ A2, const float* __restrict__ W2,
                        const float* __restrict__ bias, const float* __restrict__ ADDIN,
                        float* __restrict__ OUT, int M) {
    constexpr int BM = 128, KC = 16, TM = 8, TN = N / 16;
    constexpr int AP = BM + 4, WP = N + 4;
    constexpr int WITERS = (KC * N / 4) / 256;  // 1 for N=64, 2 for N=128
    __shared__ float A1t[KC][AP];
    __shared__ float A2t[TWO ? KC : 1][TWO ? AP : 1];
    __shared__ float W1c[KC][WP];
    __shared__ float W2c[TWO ? KC : 1][TWO ? WP : 1];

    int tid = threadIdx.x;
    int colt = tid & 15, rowt = tid >> 4;  // 16 x 16
    int i0 = blockIdx.x * BM;

    float acc[TM][TN];
#pragma unroll
    for (int m = 0; m < TM; ++m)
#pragma unroll
        for (int n = 0; n < TN; ++n) acc[m][n] = 0.f;

    for (int c0 = 0; c0 < K; c0 += KC) {
        // stage A tile(s), transposed: A1t[k][row]; 2 iters of 256 float4
#pragma unroll
        for (int j = 0; j < 2; ++j) {
            int lin = tid + j * 256;
            int row = lin >> 2, k4 = (lin & 3) * 4;
            int gr = i0 + row;
            float4 v = f4zero();
            if (gr < M) v = *(const float4*)(A1 + (size_t)gr * K + c0 + k4);
            A1t[k4 + 0][row] = v.x; A1t[k4 + 1][row] = v.y;
            A1t[k4 + 2][row] = v.z; A1t[k4 + 3][row] = v.w;
            if constexpr (TWO) {
                float4 u = f4zero();
                if (gr < M) u = *(const float4*)(A2 + (size_t)gr * K + c0 + k4);
                A2t[k4 + 0][row] = u.x; A2t[k4 + 1][row] = u.y;
                A2t[k4 + 2][row] = u.z; A2t[k4 + 3][row] = u.w;
            }
        }
        // stage W chunk(s), transposed: W1c[k][o]
#pragma unroll
        for (int j = 0; j < WITERS; ++j) {
            int lin = tid + j * 256;
            int o = lin >> 2, k4 = (lin & 3) * 4;
            float4 v = *(const float4*)(W1 + (size_t)o * K + c0 + k4);
            W1c[k4 + 0][o] = v.x; W1c[k4 + 1][o] = v.y;
            W1c[k4 + 2][o] = v.z; W1c[k4 + 3][o] = v.w;
            if constexpr (TWO) {
                float4 u = *(const float4*)(W2 + (size_t)o * K + c0 + k4);
                W2c[k4 + 0][o] = u.x; W2c[k4 + 1][o] = u.y;
                W2c[k4 + 2][o] = u.z; W2c[k4 + 3][o] = u.w;
            }
        }
        __syncthreads();
#pragma unroll
        for (int k = 0; k < KC; ++k) {
            float a1[TM];
            *(float4*)&a1[0] = *(const float4*)&A1t[k][rowt * TM];
            *(float4*)&a1[4] = *(const float4*)&A1t[k][rowt * TM + 4];
            float w1[TN];
#pragma unroll
            for (int n4 = 0; n4 < TN; n4 += 4)
                *(float4*)&w1[n4] = *(const float4*)&W1c[k][colt * TN + n4];
#pragma unroll
            for (int m = 0; m < TM; ++m)
#pragma unroll
                for (int n = 0; n < TN; ++n) acc[m][n] += a1[m] * w1[n];
            if constexpr (TWO) {
                float a2[TM];
                *(float4*)&a2[0] = *(const float4*)&A2t[k][rowt * TM];
                *(float4*)&a2[4] = *(const float4*)&A2t[k][rowt * TM + 4];
                float w2[TN];
#pragma unroll
                for (int n4 = 0; n4 < TN; n4 += 4)
                    *(float4*)&w2[n4] = *(const float4*)&W2c[k][colt * TN + n4];
#pragma unroll
                for (int m = 0; m < TM; ++m)
#pragma unroll
                    for (int n = 0; n < TN; ++n) acc[m][n] += a2[m] * w2[n];
            }
        }
        __syncthreads();
    }
    // epilogue
#pragma unroll
    for (int m = 0; m < TM; ++m) {
        int gr = i0 + rowt * TM + m;
        if (gr >= M) continue;
#pragma unroll
        for (int n4 = 0; n4 < TN; n4 += 4) {
            int col = colt * TN + n4;
            float4 v = make_float4(acc[m][n4], acc[m][n4 + 1], acc[m][n4 + 2], acc[m][n4 + 3]);
            if constexpr (HASBIAS) {
                float4 b = *(const float4*)(bias + col);
                v.x += b.x; v.y += b.y; v.z += b.z; v.w += b.w;
            }
            if constexpr (HASADD) {
                float4 a = *(const float4*)(ADDIN + (size_t)gr * N + col);
                v.x += a.x; v.y += a.y; v.z += a.z; v.w += a.w;
            }
            if constexpr (RELU) {
                v.x = fmaxf(v.x, 0.f); v.y = fmaxf(v.y, 0.f);
                v.z = fmaxf(v.z, 0.f); v.w = fmaxf(v.w, 0.f);
            }
            *(float4*)(OUT + (size_t)gr * N + col) = v;
        }
    }
}

// ---------------- pooling (batch is sorted) ----------------

__global__ void pool_kernel(const float* __restrict__ H, const int* __restrict__ batch,
                            float* __restrict__ G, int n) {
    const int CHUNK = 128;
    int f = threadIdx.x;  // 64 threads
    int start = blockIdx.x * CHUNK;
    if (start >= n) return;
    int end = start + CHUNK; if (end > n) end = n;
    int cur = batch[start];
    float acc = 0.f;
    for (int i = start; i < end; ++i) {
        int b = batch[i];
        if (b != cur) { atomicAdd(&G[(size_t)cur * 64 + f], acc); acc = 0.f; cur = b; }
        acc += H[(size_t)i * 64 + f];
    }
    atomicAdd(&G[(size_t)cur * 64 + f], acc);
}

// ---------------- MLP head + log_softmax ----------------

__global__ void mlp_head(const float* __restrict__ G, const float* __restrict__ fc1w,
                         const float* __restrict__ fc1b, const float* __restrict__ fc2w,
                         const float* __restrict__ fc2b, float* __restrict__ out) {
    int g = blockIdx.x;
    int t = threadIdx.x;  // 64
    __shared__ float gr[64], tt[64], sc[32], red[2];
    gr[t] = G[(size_t)g * 64 + t];
    __syncthreads();
    float acc = fc1b[t];
#pragma unroll
    for (int k = 0; k < 64; ++k) acc += gr[k] * fc1w[t * 64 + k];
    tt[t] = fmaxf(acc, 0.f);
    __syncthreads();
    if (t < 32) {
        float s = fc2b[t];
#pragma unroll
        for (int k = 0; k < 64; ++k) s += tt[k] * fc2w[t * 64 + k];
        sc[t] = s;
    }
    __syncthreads();
    if (t == 0) {
        float mx = sc[0];
        for (int c = 1; c < 32; ++c) mx = fmaxf(mx, sc[c]);
        float sum = 0.f;
        for (int c = 0; c < 32; ++c) sum += expf(sc[c] - mx);
        red[0] = mx; red[1] = logf(sum);
    }
    __syncthreads();
    if (t < 32) out[(size_t)g * 32 + t] = sc[t] - red[0] - red[1];
}

// ---------------- launch ----------------

extern "C" void kernel_launch(void* const* d_in, const int* in_sizes, int n_in,
                              void* d_out, int out_size, void* d_ws, size_t ws_size,
                              hipStream_t stream) {
    const float* x       = (const float*)d_in[0];
    const int*   edge    = (const int*)d_in[1];   // [2][E]: row0=src, row1=dst
    const int*   batch   = (const int*)d_in[2];
    const float* w1_rel  = (const float*)d_in[3];
    const float* b1      = (const float*)d_in[4];
    const float* w1_root = (const float*)d_in[5];
    const float* w2_rel  = (const float*)d_in[6];
    const float* b2      = (const float*)d_in[7];
    const float* w2_root = (const float*)d_in[8];
    const float* w3_rel  = (const float*)d_in[9];
    const float* b3      = (const float*)d_in[10];
    const float* w3_root = (const float*)d_in[11];
    const float* fc1w    = (const float*)d_in[12];
    const float* fc1b    = (const float*)d_in[13];
    const float* fc2w    = (const float*)d_in[14];
    const float* fc2b    = (const float*)d_in[15];
    float* out = (float*)d_out;

    char* p = (char*)d_ws;
    size_t used = 0;
    auto alloc = [&](size_t bytes) {
        char* r = p + used;
        used += (bytes + 255) & ~(size_t)255;
        return r;
    };
    int*   rowptr = (int*)alloc((N_NODES + 1) * sizeof(int));
    int*   cursor = (int*)alloc(N_NODES * sizeof(int));
    int*   csr    = (int*)alloc(N_EDGES * sizeof(int));
    int*   bsum   = (int*)alloc(SCAN_NB * sizeof(int));
    float* A      = (float*)alloc((size_t)N_NODES * 128 * sizeof(float));  // aggr1; later C|D
    float* B      = (float*)alloc((size_t)N_NODES * 128 * sizeof(float));  // h1;    later E
    float* G      = (float*)alloc((size_t)N_GRAPHS * 64 * sizeof(float));

    if (used > ws_size) return;  // clean bail instead of wild writes

    float* C = A;                         // [N,64]  y2 / h2
    float* D = A + (size_t)N_NODES * 64;  // [N,64]  aggr2 / y3 / h3
    float* E = B;                         // [N,64]  aggr3 (h1 dead by then)

    // CSR build (shared by all 3 layers)
    zero_int_kernel<<<(N_NODES + 256) / 256, 256, 0, stream>>>(rowptr, N_NODES + 1);
    hist_kernel<<<(N_EDGES + 255) / 256, 256, 0, stream>>>(edge, rowptr);
    scan_reduce_kernel<<<SCAN_NB, 256, 0, stream>>>(rowptr, bsum);
    scan_sums_kernel<<<1, 64, 0, stream>>>(bsum);
    scan_apply_kernel<<<SCAN_NB, 256, 0, stream>>>(rowptr, bsum);
    cursor_kernel<<<(N_NODES + 255) / 256, 256, 0, stream>>>(rowptr, cursor);
    scatter_kernel<<<(N_EDGES + 255) / 256, 256, 0, stream>>>(edge, cursor, csr);

    int gblk = (N_NODES + 127) / 128;

    // Layer 1: aggr1 = segsum(x); h1 = relu(aggr1@w1_rel.T + x@w1_root.T + b1)
    aggregate_v2<64, 64><<<(N_NODES + 3) / 4, 256, 0, stream>>>(x, rowptr, csr, A);
    gemm_v2<128, 128, true, true, false, true>
        <<<gblk, 256, 0, stream>>>(A, w1_rel, x, w1_root, b1, nullptr, B, N_NODES);

    // Layer 2 (transform-first): y2 = h1@w2_rel.T; aggr2 = segsum(y2);
    // h2 = relu(aggr2 + h1@w2_root.T + b2)
    gemm_v2<128, 64, false, false, false, false>
        <<<gblk, 256, 0, stream>>>(B, w2_rel, nullptr, nullptr, nullptr, nullptr, C, N_NODES);
    aggregate_v2<32, 32><<<(N_NODES + 7) / 8, 256, 0, stream>>>(C, rowptr, csr, D);
    gemm_v2<128, 64, false, true, true, true>
        <<<gblk, 256, 0, stream>>>(B, w2_root, nullptr, nullptr, b2, D, C, N_NODES);

    // Layer 3: y3 = h2@w3_rel.T; aggr3 = segsum(y3); h3 = aggr3 + h2@w3_root.T + b3
    gemm_v2<64, 64, false, false, false, false>
        <<<gblk, 256, 0, stream>>>(C, w3_rel, nullptr, nullptr, nullptr, nullptr, D, N_NODES);
    aggregate_v2<32, 32><<<(N_NODES + 7) / 8, 256, 0, stream>>>(D, rowptr, csr, E);
    gemm_v2<64, 64, false, false, true, true>
        <<<gblk, 256, 0, stream>>>(C, w3_root, nullptr, nullptr, b3, E, D, N_NODES);

    // Pool + head
    zero_float_kernel<<<(N_GRAPHS * 64 + 255) / 256, 256, 0, stream>>>(G, N_GRAPHS * 64);
    pool_kernel<<<(N_NODES + 127) / 128, 64, 0, stream>>>(D, batch, G, N_NODES);
    mlp_head<<<N_GRAPHS, 64, 0, stream>>>(G, fc1w, fc1b, fc2w, fc2b, out);
}

// Round 10
// 392.179 us; speedup vs baseline: 1.4843x; 1.0874x over previous
//
#include <hip/hip_runtime.h>

#define N_NODES  50000
#define N_EDGES  600000
#define N_GRAPHS 512

#define SCAN_N   (N_NODES + 1)
#define SCAN_BPB 1024                                   // elements per scan block
#define SCAN_NB  ((SCAN_N + SCAN_BPB - 1) / SCAN_BPB)   // 49

static __device__ __forceinline__ float4 f4zero() { return make_float4(0.f, 0.f, 0.f, 0.f); }

// bf16 helpers (RNE pack, shift unpack)
static __device__ __forceinline__ unsigned f2bf(float f) {
    unsigned u = __float_as_uint(f);
    return (u + 0x7FFFu + ((u >> 16) & 1u)) >> 16;
}
static __device__ __forceinline__ float bflo(unsigned v) { return __uint_as_float(v << 16); }
static __device__ __forceinline__ float bfhi(unsigned v) { return __uint_as_float(v & 0xFFFF0000u); }

// ---------------- tiny init kernels (avoid hipMemsetAsync under capture) ----

__global__ void zero_int_kernel(int* __restrict__ p, int n) {
    int i = blockIdx.x * blockDim.x + threadIdx.x;
    if (i < n) p[i] = 0;
}
__global__ void zero_float_kernel(float* __restrict__ p, int n) {
    int i = blockIdx.x * blockDim.x + threadIdx.x;
    if (i < n) p[i] = 0.f;
}

// ---------------- fp32 -> bf16 conversion (4 floats / thread) --------------

__global__ void f2bf_kernel(const float* __restrict__ in, uint2* __restrict__ outp, int n4) {
    int i = blockIdx.x * blockDim.x + threadIdx.x;
    if (i >= n4) return;
    float4 v = ((const float4*)in)[i];
    uint2 o;
    o.x = f2bf(v.x) | (f2bf(v.y) << 16);
    o.y = f2bf(v.z) | (f2bf(v.w) << 16);
    outp[i] = o;
}

// ---------------- CSR build ----------------

__global__ void hist_kernel(const int* __restrict__ edge, int* __restrict__ rowptr) {
    int e = blockIdx.x * blockDim.x + threadIdx.x;
    if (e < N_EDGES) atomicAdd(&rowptr[edge[N_EDGES + e] + 1], 1);
}

__global__ void scan_reduce_kernel(const int* __restrict__ data, int* __restrict__ bsum) {
    __shared__ int red[256];
    int b = blockIdx.x, t = threadIdx.x;
    int base = b * SCAN_BPB + t * 4;
    int s = 0;
#pragma unroll
    for (int j = 0; j < 4; ++j) {
        int idx = base + j;
        if (idx < SCAN_N) s += data[idx];
    }
    red[t] = s;
    __syncthreads();
    for (int off = 128; off > 0; off >>= 1) {
        if (t < off) red[t] += red[t + off];
        __syncthreads();
    }
    if (t == 0) bsum[b] = red[0];
}

__global__ void scan_sums_kernel(int* __restrict__ bsum) {
    __shared__ int sh[SCAN_NB];
    int t = threadIdx.x;
    if (t < SCAN_NB) sh[t] = bsum[t];
    __syncthreads();
    if (t == 0) {
        int run = 0;
        for (int i = 0; i < SCAN_NB; ++i) { int v = sh[i]; sh[i] = run; run += v; }
    }
    __syncthreads();
    if (t < SCAN_NB) bsum[t] = sh[t];
}

__global__ void scan_apply_kernel(int* __restrict__ data, const int* __restrict__ bexc) {
    __shared__ int th[256];
    int b = blockIdx.x, t = threadIdx.x;
    int base = b * SCAN_BPB + t * 4;
    int v[4];
    int s = 0;
#pragma unroll
    for (int j = 0; j < 4; ++j) {
        int idx = base + j;
        v[j] = (idx < SCAN_N) ? data[idx] : 0;
        s += v[j];
    }
    th[t] = s;
    __syncthreads();
    for (int off = 1; off < 256; off <<= 1) {
        int x = (t >= off) ? th[t - off] : 0;
        __syncthreads();
        th[t] += x;
        __syncthreads();
    }
    int run = bexc[b] + th[t] - s;
#pragma unroll
    for (int j = 0; j < 4; ++j) {
        int idx = base + j;
        run += v[j];
        if (idx < SCAN_N) data[idx] = run;
    }
}

__global__ void cursor_kernel(const int* __restrict__ rowptr, int* __restrict__ cursor) {
    int i = blockIdx.x * blockDim.x + threadIdx.x;
    if (i < N_NODES) cursor[i] = rowptr[i];
}

__global__ void scatter_kernel(const int* __restrict__ edge, int* __restrict__ cursor,
                               int* __restrict__ csr) {
    int e = blockIdx.x * blockDim.x + threadIdx.x;
    if (e < N_EDGES) {
        int d = edge[N_EDGES + e];
        int p = atomicAdd(&cursor[d], 1);
        csr[p] = edge[e];
    }
}

// ---------------- bf16 edge aggregation: uint2 lanes + 4-deep ILP ----------
// Row = 4*LPN bf16 features; lane owns features [4*lane, 4*lane+4).
// fp32 accumulation; output fp32.

template <int LPN>
__global__ void aggregate_bf16(const unsigned short* __restrict__ Xb,
                               const int* __restrict__ rowptr,
                               const int* __restrict__ csr, float* __restrict__ OUT) {
    constexpr int NPB = 256 / LPN;
    int grp = threadIdx.x / LPN, lane = threadIdx.x % LPN;
    int i = blockIdx.x * NPB + grp;
    if (i >= N_NODES) return;
    const uint2* __restrict__ X2 = (const uint2*)Xb;
    int s = rowptr[i], e = rowptr[i + 1];
    float a0 = 0.f, a1 = 0.f, a2 = 0.f, a3 = 0.f;
    float b0 = 0.f, b1 = 0.f, b2 = 0.f, b3 = 0.f;
    int p = s;
    for (; p + 4 <= e; p += 4) {
        int j0 = csr[p + 0], j1 = csr[p + 1], j2 = csr[p + 2], j3 = csr[p + 3];
        uint2 v0 = X2[(size_t)j0 * LPN + lane];
        uint2 v1 = X2[(size_t)j1 * LPN + lane];
        uint2 v2 = X2[(size_t)j2 * LPN + lane];
        uint2 v3 = X2[(size_t)j3 * LPN + lane];
        a0 += bflo(v0.x) + bflo(v1.x); a1 += bfhi(v0.x) + bfhi(v1.x);
        a2 += bflo(v0.y) + bflo(v1.y); a3 += bfhi(v0.y) + bfhi(v1.y);
        b0 += bflo(v2.x) + bflo(v3.x); b1 += bfhi(v2.x) + bfhi(v3.x);
        b2 += bflo(v2.y) + bflo(v3.y); b3 += bfhi(v2.y) + bfhi(v3.y);
    }
    if (p + 2 <= e) {
        int j0 = csr[p], j1 = csr[p + 1];
        uint2 v0 = X2[(size_t)j0 * LPN + lane];
        uint2 v1 = X2[(size_t)j1 * LPN + lane];
        a0 += bflo(v0.x) + bflo(v1.x); a1 += bfhi(v0.x) + bfhi(v1.x);
        a2 += bflo(v0.y) + bflo(v1.y); a3 += bfhi(v0.y) + bfhi(v1.y);
        p += 2;
    }
    if (p < e) {
        uint2 v = X2[(size_t)csr[p] * LPN + lane];
        b0 += bflo(v.x); b1 += bfhi(v.x); b2 += bflo(v.y); b3 += bfhi(v.y);
    }
    float4 r = make_float4(a0 + b0, a1 + b1, a2 + b2, a3 + b3);
    ((float4*)OUT)[(size_t)i * LPN + lane] = r;
}

// ---------------- fused node GEMM v3 ----------------
// BM=64, NT=64 (blockIdx.y tiles wider outputs), KC=16, TM=4, TN=4.
// Padded LDS: every staging write & compute read is <=2-way (free).
// OUT[i][o] = act( A1[i,:]@W1[o,:] (+A2@W2) (+ADDIN[i,o]) (+bias[o]) ), o global.
// BF16OUT packs the result to bf16 (for gather operands).
template <int K, bool TWO, bool RELU, bool HASADD, bool HASBIAS, bool BF16OUT>
__launch_bounds__(256, 4)
__global__ void gemm_v3(const float* __restrict__ A1, const float* __restrict__ W1,
                        const float* __restrict__ A2, const float* __restrict__ W2,
                        const float* __restrict__ bias, const float* __restrict__ ADDIN,
                        void* __restrict__ OUT, int M, int ldo) {
    constexpr int BM = 64, NT = 64, KC = 16, TM = 4, TN = 4;
    constexpr int AP = BM + 4, WP = NT + 4;
    __shared__ float A1t[KC][AP];
    __shared__ float A2t[TWO ? KC : 1][TWO ? AP : 1];
    __shared__ float W1c[KC][WP];
    __shared__ float W2c[TWO ? KC : 1][TWO ? WP : 1];

    int tid = threadIdx.x;
    int colt = tid & 15, rowt = tid >> 4;
    int i0 = blockIdx.x * BM;
    int wcol0 = blockIdx.y * NT;

    float acc[TM][TN];
#pragma unroll
    for (int m = 0; m < TM; ++m)
#pragma unroll
        for (int n = 0; n < TN; ++n) acc[m][n] = 0.f;

    for (int c0 = 0; c0 < K; c0 += KC) {
        {   // stage A tile(s), transposed: one float4 per thread
            int row = tid >> 2, k4 = (tid & 3) * 4;
            int gr = i0 + row;
            float4 v = f4zero();
            if (gr < M) v = *(const float4*)(A1 + (size_t)gr * K + c0 + k4);
            A1t[k4 + 0][row] = v.x; A1t[k4 + 1][row] = v.y;
            A1t[k4 + 2][row] = v.z; A1t[k4 + 3][row] = v.w;
            if constexpr (TWO) {
                float4 u = f4zero();
                if (gr < M) u = *(const float4*)(A2 + (size_t)gr * K + c0 + k4);
                A2t[k4 + 0][row] = u.x; A2t[k4 + 1][row] = u.y;
                A2t[k4 + 2][row] = u.z; A2t[k4 + 3][row] = u.w;
            }
        }
        {   // stage W tile(s), transposed: one float4 per thread
            int o = tid >> 2, k4 = (tid & 3) * 4;
            float4 v = *(const float4*)(W1 + (size_t)(wcol0 + o) * K + c0 + k4);
            W1c[k4 + 0][o] = v.x; W1c[k4 + 1][o] = v.y;
            W1c[k4 + 2][o] = v.z; W1c[k4 + 3][o] = v.w;
            if constexpr (TWO) {
                float4 u = *(const float4*)(W2 + (size_t)(wcol0 + o) * K + c0 + k4);
                W2c[k4 + 0][o] = u.x; W2c[k4 + 1][o] = u.y;
                W2c[k4 + 2][o] = u.z; W2c[k4 + 3][o] = u.w;
            }
        }
        __syncthreads();
#pragma unroll
        for (int k = 0; k < KC; ++k) {
            float a1[TM], w1[TN];
            *(float4*)a1 = *(const float4*)&A1t[k][rowt * TM];
            *(float4*)w1 = *(const float4*)&W1c[k][colt * TN];
#pragma unroll
            for (int m = 0; m < TM; ++m)
#pragma unroll
                for (int n = 0; n < TN; ++n) acc[m][n] += a1[m] * w1[n];
            if constexpr (TWO) {
                float a2[TM], w2[TN];
                *(float4*)a2 = *(const float4*)&A2t[k][rowt * TM];
                *(float4*)w2 = *(const float4*)&W2c[k][colt * TN];
#pragma unroll
                for (int m = 0; m < TM; ++m)
#pragma unroll
                    for (int n = 0; n < TN; ++n) acc[m][n] += a2[m] * w2[n];
            }
        }
        __syncthreads();
    }
    // epilogue (TN==4: one float4 group per row)
#pragma unroll
    for (int m = 0; m < TM; ++m) {
        int gr = i0 + rowt * TM + m;
        if (gr >= M) continue;
        int col = wcol0 + colt * TN;
        float4 v = make_float4(acc[m][0], acc[m][1], acc[m][2], acc[m][3]);
        if constexpr (HASBIAS) {
            float4 b = *(const float4*)(bias + col);
            v.x += b.x; v.y += b.y; v.z += b.z; v.w += b.w;
        }
        if constexpr (HASADD) {
            float4 a = *(const float4*)(ADDIN + (size_t)gr * ldo + col);
            v.x += a.x; v.y += a.y; v.z += a.z; v.w += a.w;
        }
        if constexpr (RELU) {
            v.x = fmaxf(v.x, 0.f); v.y = fmaxf(v.y, 0.f);
            v.z = fmaxf(v.z, 0.f); v.w = fmaxf(v.w, 0.f);
        }
        if constexpr (BF16OUT) {
            uint2 o;
            o.x = f2bf(v.x) | (f2bf(v.y) << 16);
            o.y = f2bf(v.z) | (f2bf(v.w) << 16);
            *(uint2*)((unsigned short*)OUT + (size_t)gr * ldo + col) = o;
        } else {
            *(float4*)((float*)OUT + (size_t)gr * ldo + col) = v;
        }
    }
}

// ---------------- pooling (batch is sorted) ----------------

__global__ void pool_kernel(const float* __restrict__ H, const int* __restrict__ batch,
                            float* __restrict__ G, int n) {
    const int CHUNK = 128;
    int f = threadIdx.x;  // 64 threads
    int start = blockIdx.x * CHUNK;
    if (start >= n) return;
    int end = start + CHUNK; if (end > n) end = n;
    int cur = batch[start];
    float acc = 0.f;
    for (int i = start; i < end; ++i) {
        int b = batch[i];
        if (b != cur) { atomicAdd(&G[(size_t)cur * 64 + f], acc); acc = 0.f; cur = b; }
        acc += H[(size_t)i * 64 + f];
    }
    atomicAdd(&G[(size_t)cur * 64 + f], acc);
}

// ---------------- MLP head + log_softmax ----------------

__global__ void mlp_head(const float* __restrict__ G, const float* __restrict__ fc1w,
                         const float* __restrict__ fc1b, const float* __restrict__ fc2w,
                         const float* __restrict__ fc2b, float* __restrict__ out) {
    int g = blockIdx.x;
    int t = threadIdx.x;  // 64
    __shared__ float gr[64], tt[64], sc[32], red[2];
    gr[t] = G[(size_t)g * 64 + t];
    __syncthreads();
    float acc = fc1b[t];
#pragma unroll
    for (int k = 0; k < 64; ++k) acc += gr[k] * fc1w[t * 64 + k];
    tt[t] = fmaxf(acc, 0.f);
    __syncthreads();
    if (t < 32) {
        float s = fc2b[t];
#pragma unroll
        for (int k = 0; k < 64; ++k) s += tt[k] * fc2w[t * 64 + k];
        sc[t] = s;
    }
    __syncthreads();
    if (t == 0) {
        float mx = sc[0];
        for (int c = 1; c < 32; ++c) mx = fmaxf(mx, sc[c]);
        float sum = 0.f;
        for (int c = 0; c < 32; ++c) sum += expf(sc[c] - mx);
        red[0] = mx; red[1] = logf(sum);
    }
    __syncthreads();
    if (t < 32) out[(size_t)g * 32 + t] = sc[t] - red[0] - red[1];
}

// ---------------- launch ----------------

extern "C" void kernel_launch(void* const* d_in, const int* in_sizes, int n_in,
                              void* d_out, int out_size, void* d_ws, size_t ws_size,
                              hipStream_t stream) {
    const float* x       = (const float*)d_in[0];
    const int*   edge    = (const int*)d_in[1];   // [2][E]: row0=src, row1=dst
    const int*   batch   = (const int*)d_in[2];
    const float* w1_rel  = (const float*)d_in[3];
    const float* b1      = (const float*)d_in[4];
    const float* w1_root = (const float*)d_in[5];
    const float* w2_rel  = (const float*)d_in[6];
    const float* b2      = (const float*)d_in[7];
    const float* w2_root = (const float*)d_in[8];
    const float* w3_rel  = (const float*)d_in[9];
    const float* b3      = (const float*)d_in[10];
    const float* w3_root = (const float*)d_in[11];
    const float* fc1w    = (const float*)d_in[12];
    const float* fc1b    = (const float*)d_in[13];
    const float* fc2w    = (const float*)d_in[14];
    const float* fc2b    = (const float*)d_in[15];
    float* out = (float*)d_out;

    char* p = (char*)d_ws;
    size_t used = 0;
    auto alloc = [&](size_t bytes) {
        char* r = p + used;
        used += (bytes + 255) & ~(size_t)255;
        return r;
    };
    int*   rowptr = (int*)alloc((N_NODES + 1) * sizeof(int));
    int*   cursor = (int*)alloc(N_NODES * sizeof(int));
    int*   csr    = (int*)alloc(N_EDGES * sizeof(int));
    int*   bsum   = (int*)alloc(SCAN_NB * sizeof(int));
    float* A      = (float*)alloc((size_t)N_NODES * 128 * sizeof(float));  // region A
    float* B      = (float*)alloc((size_t)N_NODES * 128 * sizeof(float));  // region B
    float* G      = (float*)alloc((size_t)N_GRAPHS * 64 * sizeof(float));

    if (used > ws_size) return;  // clean bail instead of wild writes

    // Region aliasing timeline (each tenant dead before its region is reused):
    float*          AGG1 = A;                                   // [N,128] f32
    unsigned short* XB   = (unsigned short*)B;                  // [N,128] bf16
    float*          H1   = B;                                   // [N,128] f32 (clobbers XB)
    unsigned short* Y2B  = (unsigned short*)A;                  // [N,64] bf16 (AGG1 dead)
    float*          AGG2 = A + (size_t)N_NODES * 64;            // [N,64] f32
    float*          H2   = A;                                   // [N,64] f32 (Y2B dead)
    unsigned short* Y3B  = (unsigned short*)B;                  // [N,64] bf16 (H1 dead)
    float*          AGG3 = B + (size_t)N_NODES * 64;            // [N,64] f32
    float*          H3   = A + (size_t)N_NODES * 64;            // [N,64] f32 (AGG2 dead)

    // CSR build (shared by all 3 layers)
    zero_int_kernel<<<(N_NODES + 256) / 256, 256, 0, stream>>>(rowptr, N_NODES + 1);
    hist_kernel<<<(N_EDGES + 255) / 256, 256, 0, stream>>>(edge, rowptr);
    scan_reduce_kernel<<<SCAN_NB, 256, 0, stream>>>(rowptr, bsum);
    scan_sums_kernel<<<1, 64, 0, stream>>>(bsum);
    scan_apply_kernel<<<SCAN_NB, 256, 0, stream>>>(rowptr, bsum);
    cursor_kernel<<<(N_NODES + 255) / 256, 256, 0, stream>>>(rowptr, cursor);
    scatter_kernel<<<(N_EDGES + 255) / 256, 256, 0, stream>>>(edge, cursor, csr);

    int gblk = (N_NODES + 63) / 64;  // 782

    // Layer 1: aggr1 = segsum(x) [bf16 gather]; h1 = relu(aggr1@W1r + x@W1root + b1)
    f2bf_kernel<<<(N_NODES * 128 / 4 + 255) / 256, 256, 0, stream>>>(x, (uint2*)XB, N_NODES * 32);
    aggregate_bf16<32><<<(N_NODES + 7) / 8, 256, 0, stream>>>(XB, rowptr, csr, AGG1);
    gemm_v3<128, true, true, false, true, false>
        <<<dim3(gblk, 2), 256, 0, stream>>>(AGG1, w1_rel, x, w1_root, b1, nullptr, H1, N_NODES, 128);

    // Layer 2 (transform-first): y2 = h1@w2_rel.T (bf16 out); aggr2 = segsum(y2);
    // h2 = relu(aggr2 + h1@w2_root.T + b2)
    gemm_v3<128, false, false, false, false, true>
        <<<dim3(gblk, 1), 256, 0, stream>>>(H1, w2_rel, nullptr, nullptr, nullptr, nullptr, Y2B, N_NODES, 64);
    aggregate_bf16<16><<<(N_NODES + 15) / 16, 256, 0, stream>>>(Y2B, rowptr, csr, AGG2);
    gemm_v3<128, false, true, true, true, false>
        <<<dim3(gblk, 1), 256, 0, stream>>>(H1, w2_root, nullptr, nullptr, b2, AGG2, H2, N_NODES, 64);

    // Layer 3: y3 = h2@w3_rel.T (bf16 out); aggr3 = segsum(y3); h3 = aggr3 + h2@w3_root.T + b3
    gemm_v3<64, false, false, false, false, true>
        <<<dim3(gblk, 1), 256, 0, stream>>>(H2, w3_rel, nullptr, nullptr, nullptr, nullptr, Y3B, N_NODES, 64);
    aggregate_bf16<16><<<(N_NODES + 15) / 16, 256, 0, stream>>>(Y3B, rowptr, csr, AGG3);
    gemm_v3<64, false, false, true, true, false>
        <<<dim3(gblk, 1), 256, 0, stream>>>(H2, w3_root, nullptr, nullptr, b3, AGG3, H3, N_NODES, 64);

    // Pool + head
    zero_float_kernel<<<(N_GRAPHS * 64 + 255) / 256, 256, 0, stream>>>(G, N_GRAPHS * 64);
    pool_kernel<<<(N_NODES + 127) / 128, 64, 0, stream>>>(H3, batch, G, N_NODES);
    mlp_head<<<N_GRAPHS, 64, 0, stream>>>(G, fc1w, fc1b, fc2w, fc2b, out);
}

// Round 11
// 338.941 us; speedup vs baseline: 1.7174x; 1.1571x over previous
//
#include <hip/hip_runtime.h>

#define N_NODES  50000
#define N_EDGES  600000
#define N_GRAPHS 512

#define SCAN_N   (N_NODES + 1)
#define SCAN_BPB 1024
#define SCAN_NB  ((SCAN_N + SCAN_BPB - 1) / SCAN_BPB)   // 49

typedef __attribute__((ext_vector_type(8))) short bf16x8;
typedef __attribute__((ext_vector_type(4))) float f32x4;

// bf16 helpers (RNE pack, shift unpack)
static __device__ __forceinline__ unsigned f2bf(float f) {
    unsigned u = __float_as_uint(f);
    return (u + 0x7FFFu + ((u >> 16) & 1u)) >> 16;
}
static __device__ __forceinline__ float bflo(unsigned v) { return __uint_as_float(v << 16); }
static __device__ __forceinline__ float bfhi(unsigned v) { return __uint_as_float(v & 0xFFFF0000u); }

// ---------------- tiny init kernels ----------------

__global__ void zero_int_kernel(int* __restrict__ p, int n) {
    int i = blockIdx.x * blockDim.x + threadIdx.x;
    if (i < n) p[i] = 0;
}
__global__ void zero_float_kernel(float* __restrict__ p, int n) {
    int i = blockIdx.x * blockDim.x + threadIdx.x;
    if (i < n) p[i] = 0.f;
}

// ---------------- fp32 -> bf16 conversions ----------------

__global__ void f2bf_kernel(const float* __restrict__ in, uint2* __restrict__ outp, int n4) {
    int i = blockIdx.x * blockDim.x + threadIdx.x;
    if (i >= n4) return;
    float4 v = ((const float4*)in)[i];
    uint2 o;
    o.x = f2bf(v.x) | (f2bf(v.y) << 16);
    o.y = f2bf(v.z) | (f2bf(v.w) << 16);
    outp[i] = o;
}

// all 6 weight matrices -> one bf16 buffer (fixed offsets)
__global__ void wconv_kernel(const float* __restrict__ w1r, const float* __restrict__ w1o,
                             const float* __restrict__ w2r, const float* __restrict__ w2o,
                             const float* __restrict__ w3r, const float* __restrict__ w3o,
                             unsigned short* __restrict__ dst) {
    int i = blockIdx.x * blockDim.x + threadIdx.x;
    const float* src; int off;
    if      (i < 16384) { src = w1r; off = 0; }
    else if (i < 32768) { src = w1o; off = 16384; }
    else if (i < 40960) { src = w2r; off = 32768; }
    else if (i < 49152) { src = w2o; off = 40960; }
    else if (i < 53248) { src = w3r; off = 49152; }
    else if (i < 57344) { src = w3o; off = 53248; }
    else return;
    dst[i] = (unsigned short)f2bf(src[i - off]);
}

// ---------------- CSR build ----------------

__global__ void hist_kernel(const int* __restrict__ edge, int* __restrict__ rowptr) {
    int e = blockIdx.x * blockDim.x + threadIdx.x;
    if (e < N_EDGES) atomicAdd(&rowptr[edge[N_EDGES + e] + 1], 1);
}

__global__ void scan_reduce_kernel(const int* __restrict__ data, int* __restrict__ bsum) {
    __shared__ int red[256];
    int b = blockIdx.x, t = threadIdx.x;
    int base = b * SCAN_BPB + t * 4;
    int s = 0;
#pragma unroll
    for (int j = 0; j < 4; ++j) {
        int idx = base + j;
        if (idx < SCAN_N) s += data[idx];
    }
    red[t] = s;
    __syncthreads();
    for (int off = 128; off > 0; off >>= 1) {
        if (t < off) red[t] += red[t + off];
        __syncthreads();
    }
    if (t == 0) bsum[b] = red[0];
}

__global__ void scan_sums_kernel(int* __restrict__ bsum) {
    __shared__ int sh[SCAN_NB];
    int t = threadIdx.x;
    if (t < SCAN_NB) sh[t] = bsum[t];
    __syncthreads();
    if (t == 0) {
        int run = 0;
        for (int i = 0; i < SCAN_NB; ++i) { int v = sh[i]; sh[i] = run; run += v; }
    }
    __syncthreads();
    if (t < SCAN_NB) bsum[t] = sh[t];
}

__global__ void scan_apply_kernel(int* __restrict__ data, const int* __restrict__ bexc) {
    __shared__ int th[256];
    int b = blockIdx.x, t = threadIdx.x;
    int base = b * SCAN_BPB + t * 4;
    int v[4];
    int s = 0;
#pragma unroll
    for (int j = 0; j < 4; ++j) {
        int idx = base + j;
        v[j] = (idx < SCAN_N) ? data[idx] : 0;
        s += v[j];
    }
    th[t] = s;
    __syncthreads();
    for (int off = 1; off < 256; off <<= 1) {
        int x = (t >= off) ? th[t - off] : 0;
        __syncthreads();
        th[t] += x;
        __syncthreads();
    }
    int run = bexc[b] + th[t] - s;
#pragma unroll
    for (int j = 0; j < 4; ++j) {
        int idx = base + j;
        run += v[j];
        if (idx < SCAN_N) data[idx] = run;
    }
}

__global__ void cursor_kernel(const int* __restrict__ rowptr, int* __restrict__ cursor) {
    int i = blockIdx.x * blockDim.x + threadIdx.x;
    if (i < N_NODES) cursor[i] = rowptr[i];
}

__global__ void scatter_kernel(const int* __restrict__ edge, int* __restrict__ cursor,
                               int* __restrict__ csr) {
    int e = blockIdx.x * blockDim.x + threadIdx.x;
    if (e < N_EDGES) {
        int d = edge[N_EDGES + e];
        int p = atomicAdd(&cursor[d], 1);
        csr[p] = edge[e];
    }
}

// ---------------- bf16 edge aggregation (bf16 in, bf16 out, fp32 accum) ----
// Row = 4*LPN bf16 features; lane owns 4 features; 4-deep gather ILP.

template <int LPN>
__global__ void aggregate_bf16(const unsigned short* __restrict__ Xb,
                               const int* __restrict__ rowptr,
                               const int* __restrict__ csr,
                               unsigned short* __restrict__ OUT) {
    constexpr int NPB = 256 / LPN;
    int grp = threadIdx.x / LPN, lane = threadIdx.x % LPN;
    int i = blockIdx.x * NPB + grp;
    if (i >= N_NODES) return;
    const uint2* __restrict__ X2 = (const uint2*)Xb;
    int s = rowptr[i], e = rowptr[i + 1];
    float a0 = 0.f, a1 = 0.f, a2 = 0.f, a3 = 0.f;
    float b0 = 0.f, b1 = 0.f, b2 = 0.f, b3 = 0.f;
    int p = s;
    for (; p + 4 <= e; p += 4) {
        int j0 = csr[p + 0], j1 = csr[p + 1], j2 = csr[p + 2], j3 = csr[p + 3];
        uint2 v0 = X2[(size_t)j0 * LPN + lane];
        uint2 v1 = X2[(size_t)j1 * LPN + lane];
        uint2 v2 = X2[(size_t)j2 * LPN + lane];
        uint2 v3 = X2[(size_t)j3 * LPN + lane];
        a0 += bflo(v0.x) + bflo(v1.x); a1 += bfhi(v0.x) + bfhi(v1.x);
        a2 += bflo(v0.y) + bflo(v1.y); a3 += bfhi(v0.y) + bfhi(v1.y);
        b0 += bflo(v2.x) + bflo(v3.x); b1 += bfhi(v2.x) + bfhi(v3.x);
        b2 += bflo(v2.y) + bflo(v3.y); b3 += bfhi(v2.y) + bfhi(v3.y);
    }
    if (p + 2 <= e) {
        int j0 = csr[p], j1 = csr[p + 1];
        uint2 v0 = X2[(size_t)j0 * LPN + lane];
        uint2 v1 = X2[(size_t)j1 * LPN + lane];
        a0 += bflo(v0.x) + bflo(v1.x); a1 += bfhi(v0.x) + bfhi(v1.x);
        a2 += bflo(v0.y) + bflo(v1.y); a3 += bfhi(v0.y) + bfhi(v1.y);
        p += 2;
    }
    if (p < e) {
        uint2 v = X2[(size_t)csr[p] * LPN + lane];
        b0 += bflo(v.x); b1 += bfhi(v.x); b2 += bflo(v.y); b3 += bfhi(v.y);
    }
    uint2 o;
    o.x = f2bf(a0 + b0) | (f2bf(a1 + b1) << 16);
    o.y = f2bf(a2 + b2) | (f2bf(a3 + b3) << 16);
    ((uint2*)OUT)[(size_t)i * LPN + lane] = o;
}

// ---------------- MFMA GEMM ----------------
// out[m][n] = act( A1[m,:K1]@W1[n,:K1] (+ A2[m,:K2]@W2[n,:K2]) (+ADDIN) (+bias) )
// A row-major [M][K] bf16; W row-major [N][K] bf16 (= B^T, m92 pattern).
// Frag layout: lane l -> a: row l&15, k=(l>>4)*8+j (contig 16B); b identical on W.
// C/D: col = l&15, row = (l>>4)*4 + reg (m89-verified).
// Block = 4 waves; wave wv owns n-cols [wv*NT*16, ...); W frags preloaded to VGPRs.
// Block covers 4 row-tiles of 16 rows (M=50000 = 3125*16 exactly).
template <int KS1, int KS2, int NT, bool RELU, bool HASADD, bool HASBIAS, bool BF16OUT>
__launch_bounds__(256, 2)
__global__ void gemm_mfma(const unsigned short* __restrict__ A1,
                          const unsigned short* __restrict__ W1,
                          const unsigned short* __restrict__ A2,
                          const unsigned short* __restrict__ W2,
                          const float* __restrict__ bias,
                          const unsigned short* __restrict__ ADDIN,
                          void* __restrict__ OUT, int ldo) {
    constexpr int K1 = KS1 * 32, K2 = KS2 * 32;
    const int l  = threadIdx.x & 63;
    const int wv = threadIdx.x >> 6;
    const int lm = l & 15, lk = l >> 4;
    const int colbase = wv * (NT * 16);

    // preload W fragments (L2-resident, reused over all row-tiles)
    bf16x8 wf[NT][KS1 + KS2];
#pragma unroll
    for (int t = 0; t < NT; ++t) {
        int wrow = colbase + t * 16 + lm;
#pragma unroll
        for (int ks = 0; ks < KS1; ++ks)
            wf[t][ks] = *(const bf16x8*)(W1 + (size_t)wrow * K1 + ks * 32 + lk * 8);
        if constexpr (KS2 > 0) {
#pragma unroll
            for (int ks = 0; ks < KS2; ++ks)
                wf[t][KS1 + ks] = *(const bf16x8*)(W2 + (size_t)wrow * K2 + ks * 32 + lk * 8);
        }
    }

    int rt0 = blockIdx.x * 4;
    for (int r = 0; r < 4; ++r) {
        int rt = rt0 + r;
        if (rt >= N_NODES / 16) break;
        f32x4 acc[NT];
#pragma unroll
        for (int t = 0; t < NT; ++t) acc[t] = (f32x4){0.f, 0.f, 0.f, 0.f};

        const unsigned short* a1row = A1 + (size_t)(rt * 16 + lm) * K1 + lk * 8;
#pragma unroll
        for (int ks = 0; ks < KS1; ++ks) {
            bf16x8 a = *(const bf16x8*)(a1row + ks * 32);
#pragma unroll
            for (int t = 0; t < NT; ++t)
                acc[t] = __builtin_amdgcn_mfma_f32_16x16x32_bf16(a, wf[t][ks], acc[t], 0, 0, 0);
        }
        if constexpr (KS2 > 0) {
            const unsigned short* a2row = A2 + (size_t)(rt * 16 + lm) * K2 + lk * 8;
#pragma unroll
            for (int ks = 0; ks < KS2; ++ks) {
                bf16x8 a = *(const bf16x8*)(a2row + ks * 32);
#pragma unroll
                for (int t = 0; t < NT; ++t)
                    acc[t] = __builtin_amdgcn_mfma_f32_16x16x32_bf16(a, wf[t][KS1 + ks], acc[t], 0, 0, 0);
            }
        }
        // epilogue
#pragma unroll
        for (int t = 0; t < NT; ++t) {
            int n = colbase + t * 16 + lm;
            float bv = 0.f;
            if constexpr (HASBIAS) bv = bias[n];
#pragma unroll
            for (int j = 0; j < 4; ++j) {
                int m = rt * 16 + lk * 4 + j;
                float v = acc[t][j] + bv;
                if constexpr (HASADD)
                    v += __uint_as_float((unsigned)ADDIN[(size_t)m * ldo + n] << 16);
                if constexpr (RELU) v = fmaxf(v, 0.f);
                if constexpr (BF16OUT)
                    ((unsigned short*)OUT)[(size_t)m * ldo + n] = (unsigned short)f2bf(v);
                else
                    ((float*)OUT)[(size_t)m * ldo + n] = v;
            }
        }
    }
}

// ---------------- pooling (batch is sorted) ----------------

__global__ void pool_kernel(const float* __restrict__ H, const int* __restrict__ batch,
                            float* __restrict__ G, int n) {
    const int CHUNK = 128;
    int f = threadIdx.x;  // 64 threads
    int start = blockIdx.x * CHUNK;
    if (start >= n) return;
    int end = start + CHUNK; if (end > n) end = n;
    int cur = batch[start];
    float acc = 0.f;
    for (int i = start; i < end; ++i) {
        int b = batch[i];
        if (b != cur) { atomicAdd(&G[(size_t)cur * 64 + f], acc); acc = 0.f; cur = b; }
        acc += H[(size_t)i * 64 + f];
    }
    atomicAdd(&G[(size_t)cur * 64 + f], acc);
}

// ---------------- MLP head + log_softmax ----------------

__global__ void mlp_head(const float* __restrict__ G, const float* __restrict__ fc1w,
                         const float* __restrict__ fc1b, const float* __restrict__ fc2w,
                         const float* __restrict__ fc2b, float* __restrict__ out) {
    int g = blockIdx.x;
    int t = threadIdx.x;  // 64
    __shared__ float gr[64], tt[64], sc[32], red[2];
    gr[t] = G[(size_t)g * 64 + t];
    __syncthreads();
    float acc = fc1b[t];
#pragma unroll
    for (int k = 0; k < 64; ++k) acc += gr[k] * fc1w[t * 64 + k];
    tt[t] = fmaxf(acc, 0.f);
    __syncthreads();
    if (t < 32) {
        float s = fc2b[t];
#pragma unroll
        for (int k = 0; k < 64; ++k) s += tt[k] * fc2w[t * 64 + k];
        sc[t] = s;
    }
    __syncthreads();
    if (t == 0) {
        float mx = sc[0];
        for (int c = 1; c < 32; ++c) mx = fmaxf(mx, sc[c]);
        float sum = 0.f;
        for (int c = 0; c < 32; ++c) sum += expf(sc[c] - mx);
        red[0] = mx; red[1] = logf(sum);
    }
    __syncthreads();
    if (t < 32) out[(size_t)g * 32 + t] = sc[t] - red[0] - red[1];
}

// ---------------- launch ----------------

extern "C" void kernel_launch(void* const* d_in, const int* in_sizes, int n_in,
                              void* d_out, int out_size, void* d_ws, size_t ws_size,
                              hipStream_t stream) {
    const float* x       = (const float*)d_in[0];
    const int*   edge    = (const int*)d_in[1];   // [2][E]: row0=src, row1=dst
    const int*   batch   = (const int*)d_in[2];
    const float* w1_rel  = (const float*)d_in[3];
    const float* b1      = (const float*)d_in[4];
    const float* w1_root = (const float*)d_in[5];
    const float* w2_rel  = (const float*)d_in[6];
    const float* b2      = (const float*)d_in[7];
    const float* w2_root = (const float*)d_in[8];
    const float* w3_rel  = (const float*)d_in[9];
    const float* b3      = (const float*)d_in[10];
    const float* w3_root = (const float*)d_in[11];
    const float* fc1w    = (const float*)d_in[12];
    const float* fc1b    = (const float*)d_in[13];
    const float* fc2w    = (const float*)d_in[14];
    const float* fc2b    = (const float*)d_in[15];
    float* out = (float*)d_out;

    char* p = (char*)d_ws;
    size_t used = 0;
    auto alloc = [&](size_t bytes) {
        char* r = p + used;
        used += (bytes + 255) & ~(size_t)255;
        return r;
    };
    int*            rowptr = (int*)alloc((N_NODES + 1) * sizeof(int));
    int*            cursor = (int*)alloc(N_NODES * sizeof(int));
    int*            csr    = (int*)alloc(N_EDGES * sizeof(int));
    int*            bsum   = (int*)alloc(SCAN_NB * sizeof(int));
    unsigned short* wbf    = (unsigned short*)alloc(57344 * sizeof(unsigned short));
    unsigned short* bufXB  = (unsigned short*)alloc((size_t)N_NODES * 128 * 2);  // region X
    unsigned short* bufAG  = (unsigned short*)alloc((size_t)N_NODES * 128 * 2);  // region A
    unsigned short* bufH1  = (unsigned short*)alloc((size_t)N_NODES * 128 * 2);  // region H
    float*          G      = (float*)alloc((size_t)N_GRAPHS * 64 * sizeof(float));

    if (used > ws_size) return;  // clean bail instead of wild writes

    // bf16 weight views
    unsigned short* w1r_bf = wbf;          // [128][128]
    unsigned short* w1o_bf = wbf + 16384;  // [128][128]
    unsigned short* w2r_bf = wbf + 32768;  // [64][128]
    unsigned short* w2o_bf = wbf + 40960;  // [64][128]
    unsigned short* w3r_bf = wbf + 49152;  // [64][64]
    unsigned short* w3o_bf = wbf + 53248;  // [64][64]

    // Region aliasing timeline (tenant dead before reuse):
    unsigned short* XB    = bufXB;                              // [N,128] bf16
    unsigned short* AGG1b = bufAG;                              // [N,128] bf16
    unsigned short* H1b   = bufH1;                              // [N,128] bf16
    unsigned short* Y2B   = bufXB;                              // [N,64] bf16 (XB dead)
    unsigned short* AGG2b = bufXB + (size_t)N_NODES * 64;       // [N,64] bf16
    unsigned short* H2b   = bufAG;                              // [N,64] bf16 (AGG1 dead)
    unsigned short* Y3B   = bufXB;                              // [N,64] bf16 (Y2B dead)
    unsigned short* AGG3b = bufXB + (size_t)N_NODES * 64;       // [N,64] bf16 (AGG2 dead)
    float*          H3    = (float*)bufH1;                      // [N,64] f32 (H1 dead)

    // CSR build (shared by all 3 layers)
    zero_int_kernel<<<(N_NODES + 256) / 256, 256, 0, stream>>>(rowptr, N_NODES + 1);
    hist_kernel<<<(N_EDGES + 255) / 256, 256, 0, stream>>>(edge, rowptr);
    scan_reduce_kernel<<<SCAN_NB, 256, 0, stream>>>(rowptr, bsum);
    scan_sums_kernel<<<1, 64, 0, stream>>>(bsum);
    scan_apply_kernel<<<SCAN_NB, 256, 0, stream>>>(rowptr, bsum);
    cursor_kernel<<<(N_NODES + 255) / 256, 256, 0, stream>>>(rowptr, cursor);
    scatter_kernel<<<(N_EDGES + 255) / 256, 256, 0, stream>>>(edge, cursor, csr);

    // bf16 conversions
    f2bf_kernel<<<(N_NODES * 32 + 255) / 256, 256, 0, stream>>>(x, (uint2*)XB, N_NODES * 32);
    wconv_kernel<<<224, 256, 0, stream>>>(w1_rel, w1_root, w2_rel, w2_root, w3_rel, w3_root, wbf);

    int gblk = (N_NODES / 16 + 3) / 4;  // 782 blocks of 4 row-tiles

    // Layer 1: aggr1 = segsum(x); h1 = relu(aggr1@W1r + x@W1o + b1)  [concat-K MFMA]
    aggregate_bf16<32><<<(N_NODES + 7) / 8, 256, 0, stream>>>(XB, rowptr, csr, AGG1b);
    gemm_mfma<4, 4, 2, true, false, true, true>
        <<<gblk, 256, 0, stream>>>(AGG1b, w1r_bf, XB, w1o_bf, b1, nullptr, H1b, 128);

    // Layer 2: y2 = h1@W2r; aggr2 = segsum(y2); h2 = relu(aggr2 + h1@W2o + b2)
    gemm_mfma<4, 0, 1, false, false, false, true>
        <<<gblk, 256, 0, stream>>>(H1b, w2r_bf, nullptr, nullptr, nullptr, nullptr, Y2B, 64);
    aggregate_bf16<16><<<(N_NODES + 15) / 16, 256, 0, stream>>>(Y2B, rowptr, csr, AGG2b);
    gemm_mfma<4, 0, 1, true, true, true, true>
        <<<gblk, 256, 0, stream>>>(H1b, w2o_bf, nullptr, nullptr, b2, AGG2b, H2b, 64);

    // Layer 3: y3 = h2@W3r; aggr3 = segsum(y3); h3 = aggr3 + h2@W3o + b3  (fp32 out)
    gemm_mfma<2, 0, 1, false, false, false, true>
        <<<gblk, 256, 0, stream>>>(H2b, w3r_bf, nullptr, nullptr, nullptr, nullptr, Y3B, 64);
    aggregate_bf16<16><<<(N_NODES + 15) / 16, 256, 0, stream>>>(Y3B, rowptr, csr, AGG3b);
    gemm_mfma<2, 0, 1, false, true, true, false>
        <<<gblk, 256, 0, stream>>>(H2b, w3o_bf, nullptr, nullptr, b3, AGG3b, H3, 64);

    // Pool + head
    zero_float_kernel<<<(N_GRAPHS * 64 + 255) / 256, 256, 0, stream>>>(G, N_GRAPHS * 64);
    pool_kernel<<<(N_NODES + 127) / 128, 64, 0, stream>>>(H3, batch, G, N_NODES);
    mlp_head<<<N_GRAPHS, 64, 0, stream>>>(G, fc1w, fc1b, fc2w, fc2b, out);
}

// Round 12
// 321.688 us; speedup vs baseline: 1.8095x; 1.0536x over previous
//
#include <hip/hip_runtime.h>

#define N_NODES  50000
#define N_EDGES  600000
#define N_GRAPHS 512

#define SCAN_N   (N_NODES + 1)
#define SCAN_BPB 1024
#define SCAN_NB  ((SCAN_N + SCAN_BPB - 1) / SCAN_BPB)   // 49

typedef __attribute__((ext_vector_type(8))) short bf16x8;
typedef __attribute__((ext_vector_type(4))) float f32x4;

// bf16 helpers (RNE pack, shift unpack)
static __device__ __forceinline__ unsigned f2bf(float f) {
    unsigned u = __float_as_uint(f);
    return (u + 0x7FFFu + ((u >> 16) & 1u)) >> 16;
}
static __device__ __forceinline__ float bflo(unsigned v) { return __uint_as_float(v << 16); }
static __device__ __forceinline__ float bfhi(unsigned v) { return __uint_as_float(v & 0xFFFF0000u); }

static __device__ __forceinline__ void addv8(float* acc, uint4 v) {
    acc[0] += bflo(v.x); acc[1] += bfhi(v.x);
    acc[2] += bflo(v.y); acc[3] += bfhi(v.y);
    acc[4] += bflo(v.z); acc[5] += bfhi(v.z);
    acc[6] += bflo(v.w); acc[7] += bfhi(v.w);
}

// ---------------- tiny init kernels ----------------

__global__ void zero_int_kernel(int* __restrict__ p, int n) {
    int i = blockIdx.x * blockDim.x + threadIdx.x;
    if (i < n) p[i] = 0;
}
__global__ void zero_float_kernel(float* __restrict__ p, int n) {
    int i = blockIdx.x * blockDim.x + threadIdx.x;
    if (i < n) p[i] = 0.f;
}

// ---------------- fp32 -> bf16 conversions ----------------

__global__ void f2bf_kernel(const float* __restrict__ in, uint2* __restrict__ outp, int n4) {
    int i = blockIdx.x * blockDim.x + threadIdx.x;
    if (i >= n4) return;
    float4 v = ((const float4*)in)[i];
    uint2 o;
    o.x = f2bf(v.x) | (f2bf(v.y) << 16);
    o.y = f2bf(v.z) | (f2bf(v.w) << 16);
    outp[i] = o;
}

// all 6 weight matrices -> one bf16 buffer (fixed offsets; r/o pairs contiguous)
__global__ void wconv_kernel(const float* __restrict__ w1r, const float* __restrict__ w1o,
                             const float* __restrict__ w2r, const float* __restrict__ w2o,
                             const float* __restrict__ w3r, const float* __restrict__ w3o,
                             unsigned short* __restrict__ dst) {
    int i = blockIdx.x * blockDim.x + threadIdx.x;
    const float* src; int off;
    if      (i < 16384) { src = w1r; off = 0; }
    else if (i < 32768) { src = w1o; off = 16384; }
    else if (i < 40960) { src = w2r; off = 32768; }
    else if (i < 49152) { src = w2o; off = 40960; }
    else if (i < 53248) { src = w3r; off = 49152; }
    else if (i < 57344) { src = w3o; off = 53248; }
    else return;
    dst[i] = (unsigned short)f2bf(src[i - off]);
}

// ---------------- CSR build ----------------

__global__ void hist_kernel(const int* __restrict__ edge, int* __restrict__ rowptr) {
    int e = blockIdx.x * blockDim.x + threadIdx.x;
    if (e < N_EDGES) atomicAdd(&rowptr[edge[N_EDGES + e] + 1], 1);
}

__global__ void scan_reduce_kernel(const int* __restrict__ data, int* __restrict__ bsum) {
    __shared__ int red[256];
    int b = blockIdx.x, t = threadIdx.x;
    int base = b * SCAN_BPB + t * 4;
    int s = 0;
#pragma unroll
    for (int j = 0; j < 4; ++j) {
        int idx = base + j;
        if (idx < SCAN_N) s += data[idx];
    }
    red[t] = s;
    __syncthreads();
    for (int off = 128; off > 0; off >>= 1) {
        if (t < off) red[t] += red[t + off];
        __syncthreads();
    }
    if (t == 0) bsum[b] = red[0];
}

__global__ void scan_sums_kernel(int* __restrict__ bsum) {
    __shared__ int sh[SCAN_NB];
    int t = threadIdx.x;
    if (t < SCAN_NB) sh[t] = bsum[t];
    __syncthreads();
    if (t == 0) {
        int run = 0;
        for (int i = 0; i < SCAN_NB; ++i) { int v = sh[i]; sh[i] = run; run += v; }
    }
    __syncthreads();
    if (t < SCAN_NB) bsum[t] = sh[t];
}

// scan_apply + cursor init fused
__global__ void scan_apply_kernel(int* __restrict__ data, const int* __restrict__ bexc,
                                  int* __restrict__ cursor) {
    __shared__ int th[256];
    int b = blockIdx.x, t = threadIdx.x;
    int base = b * SCAN_BPB + t * 4;
    int v[4];
    int s = 0;
#pragma unroll
    for (int j = 0; j < 4; ++j) {
        int idx = base + j;
        v[j] = (idx < SCAN_N) ? data[idx] : 0;
        s += v[j];
    }
    th[t] = s;
    __syncthreads();
    for (int off = 1; off < 256; off <<= 1) {
        int x = (t >= off) ? th[t - off] : 0;
        __syncthreads();
        th[t] += x;
        __syncthreads();
    }
    int run = bexc[b] + th[t] - s;
#pragma unroll
    for (int j = 0; j < 4; ++j) {
        int idx = base + j;
        run += v[j];
        if (idx < SCAN_N) {
            data[idx] = run;
            if (idx < N_NODES) cursor[idx] = run;
        }
    }
}

__global__ void scatter_kernel(const int* __restrict__ edge, int* __restrict__ cursor,
                               int* __restrict__ csr) {
    int e = blockIdx.x * blockDim.x + threadIdx.x;
    if (e < N_EDGES) {
        int d = edge[N_EDGES + e];
        int p = atomicAdd(&cursor[d], 1);
        csr[p] = edge[e];
    }
}

// ---------------- bf16 aggregation, uint4 lanes (16B), 4-deep ILP ----------
// Row = LPN*8 bf16 features; lane owns 8 features.
// MODE 0: OUT = bf16(aggr)                      (layer-1 pre-GEMM)
// MODE 1: OUT = bf16(relu(aggr + ROOT))         (layer-2 h)
// MODE 2: OUT = f32(aggr + ROOT)                (layer-3 h, feeds pool)
template <int LPN, int MODE>
__global__ void aggregate_u4(const unsigned short* __restrict__ Xb,
                             const int* __restrict__ rowptr,
                             const int* __restrict__ csr,
                             const unsigned short* __restrict__ ROOT,
                             void* __restrict__ OUT) {
    constexpr int NPB = 256 / LPN;
    int grp = threadIdx.x / LPN, lane = threadIdx.x % LPN;
    int i = blockIdx.x * NPB + grp;
    if (i >= N_NODES) return;
    const uint4* __restrict__ X4 = (const uint4*)Xb;
    int s = rowptr[i], e = rowptr[i + 1];
    float a[8] = {0.f}, b[8] = {0.f};
    int p = s;
    for (; p + 4 <= e; p += 4) {
        int j0 = csr[p + 0], j1 = csr[p + 1], j2 = csr[p + 2], j3 = csr[p + 3];
        uint4 v0 = X4[(size_t)j0 * LPN + lane];
        uint4 v1 = X4[(size_t)j1 * LPN + lane];
        uint4 v2 = X4[(size_t)j2 * LPN + lane];
        uint4 v3 = X4[(size_t)j3 * LPN + lane];
        addv8(a, v0); addv8(a, v1); addv8(b, v2); addv8(b, v3);
    }
    if (p + 2 <= e) {
        uint4 v0 = X4[(size_t)csr[p] * LPN + lane];
        uint4 v1 = X4[(size_t)csr[p + 1] * LPN + lane];
        addv8(a, v0); addv8(a, v1);
        p += 2;
    }
    if (p < e) {
        uint4 v = X4[(size_t)csr[p] * LPN + lane];
        addv8(b, v);
    }
    float f[8];
#pragma unroll
    for (int k = 0; k < 8; ++k) f[k] = a[k] + b[k];
    if constexpr (MODE != 0) {
        uint4 r = ((const uint4*)ROOT)[(size_t)i * LPN + lane];
        f[0] += bflo(r.x); f[1] += bfhi(r.x);
        f[2] += bflo(r.y); f[3] += bfhi(r.y);
        f[4] += bflo(r.z); f[5] += bfhi(r.z);
        f[6] += bflo(r.w); f[7] += bfhi(r.w);
    }
    if constexpr (MODE == 1) {
#pragma unroll
        for (int k = 0; k < 8; ++k) f[k] = fmaxf(f[k], 0.f);
    }
    if constexpr (MODE == 2) {
        float* row = (float*)OUT + (size_t)i * (LPN * 8) + lane * 8;
        *(float4*)row       = make_float4(f[0], f[1], f[2], f[3]);
        *(float4*)(row + 4) = make_float4(f[4], f[5], f[6], f[7]);
    } else {
        uint4 o;
        o.x = f2bf(f[0]) | (f2bf(f[1]) << 16);
        o.y = f2bf(f[2]) | (f2bf(f[3]) << 16);
        o.z = f2bf(f[4]) | (f2bf(f[5]) << 16);
        o.w = f2bf(f[6]) | (f2bf(f[7]) << 16);
        ((uint4*)OUT)[(size_t)i * LPN + lane] = o;
    }
}

// ---------------- MFMA GEMM (layer 1, concat-K, single output) -------------
// H1 = relu(A1@W1^T + A2@W2^T + bias); all bf16 in, bf16 out.
template <int KS1, int KS2, int NT>
__launch_bounds__(256, 2)
__global__ void gemm_mfma(const unsigned short* __restrict__ A1,
                          const unsigned short* __restrict__ W1,
                          const unsigned short* __restrict__ A2,
                          const unsigned short* __restrict__ W2,
                          const float* __restrict__ bias,
                          unsigned short* __restrict__ OUT, int ldo) {
    constexpr int K1 = KS1 * 32, K2 = KS2 * 32;
    const int l  = threadIdx.x & 63;
    const int wv = threadIdx.x >> 6;
    const int lm = l & 15, lk = l >> 4;
    const int colbase = wv * (NT * 16);

    bf16x8 wf[NT][KS1 + KS2];
#pragma unroll
    for (int t = 0; t < NT; ++t) {
        int wrow = colbase + t * 16 + lm;
#pragma unroll
        for (int ks = 0; ks < KS1; ++ks)
            wf[t][ks] = *(const bf16x8*)(W1 + (size_t)wrow * K1 + ks * 32 + lk * 8);
#pragma unroll
        for (int ks = 0; ks < KS2; ++ks)
            wf[t][KS1 + ks] = *(const bf16x8*)(W2 + (size_t)wrow * K2 + ks * 32 + lk * 8);
    }

    int rt0 = blockIdx.x * 4;
    for (int r = 0; r < 4; ++r) {
        int rt = rt0 + r;
        if (rt >= N_NODES / 16) break;
        f32x4 acc[NT];
#pragma unroll
        for (int t = 0; t < NT; ++t) acc[t] = (f32x4){0.f, 0.f, 0.f, 0.f};

        const unsigned short* a1row = A1 + (size_t)(rt * 16 + lm) * K1 + lk * 8;
#pragma unroll
        for (int ks = 0; ks < KS1; ++ks) {
            bf16x8 a = *(const bf16x8*)(a1row + ks * 32);
#pragma unroll
            for (int t = 0; t < NT; ++t)
                acc[t] = __builtin_amdgcn_mfma_f32_16x16x32_bf16(a, wf[t][ks], acc[t], 0, 0, 0);
        }
        const unsigned short* a2row = A2 + (size_t)(rt * 16 + lm) * K2 + lk * 8;
#pragma unroll
        for (int ks = 0; ks < KS2; ++ks) {
            bf16x8 a = *(const bf16x8*)(a2row + ks * 32);
#pragma unroll
            for (int t = 0; t < NT; ++t)
                acc[t] = __builtin_amdgcn_mfma_f32_16x16x32_bf16(a, wf[t][KS1 + ks], acc[t], 0, 0, 0);
        }
#pragma unroll
        for (int t = 0; t < NT; ++t) {
            int n = colbase + t * 16 + lm;
            float bv = bias[n];
#pragma unroll
            for (int j = 0; j < 4; ++j) {
                int m = rt * 16 + lk * 4 + j;
                float v = fmaxf(acc[t][j] + bv, 0.f);
                OUT[(size_t)m * ldo + n] = (unsigned short)f2bf(v);
            }
        }
    }
}

// ---------------- MFMA dual GEMM (layers 2/3) ------------------------------
// W = [128][K] = Wrel rows 0..63 ‖ Wroot rows 64..127 (contiguous in wbf).
// n<64:  Y[m][n]      = A@Wrel   (bf16, no bias)
// n>=64: ROOT[m][n-64]= A@Wroot + bias[n-64] (bf16)
template <int KS>
__launch_bounds__(256, 2)
__global__ void gemm_dual(const unsigned short* __restrict__ A,
                          const unsigned short* __restrict__ W,
                          const float* __restrict__ bias,
                          unsigned short* __restrict__ OUTY,
                          unsigned short* __restrict__ OUTR) {
    constexpr int K = KS * 32, NT = 2;
    const int l  = threadIdx.x & 63;
    const int wv = threadIdx.x >> 6;
    const int lm = l & 15, lk = l >> 4;
    const int colbase = wv * (NT * 16);

    bf16x8 wf[NT][KS];
#pragma unroll
    for (int t = 0; t < NT; ++t) {
        int wrow = colbase + t * 16 + lm;
#pragma unroll
        for (int ks = 0; ks < KS; ++ks)
            wf[t][ks] = *(const bf16x8*)(W + (size_t)wrow * K + ks * 32 + lk * 8);
    }

    int rt0 = blockIdx.x * 4;
    for (int r = 0; r < 4; ++r) {
        int rt = rt0 + r;
        if (rt >= N_NODES / 16) break;
        f32x4 acc[NT];
#pragma unroll
        for (int t = 0; t < NT; ++t) acc[t] = (f32x4){0.f, 0.f, 0.f, 0.f};

        const unsigned short* arow = A + (size_t)(rt * 16 + lm) * K + lk * 8;
#pragma unroll
        for (int ks = 0; ks < KS; ++ks) {
            bf16x8 a = *(const bf16x8*)(arow + ks * 32);
#pragma unroll
            for (int t = 0; t < NT; ++t)
                acc[t] = __builtin_amdgcn_mfma_f32_16x16x32_bf16(a, wf[t][ks], acc[t], 0, 0, 0);
        }
#pragma unroll
        for (int t = 0; t < NT; ++t) {
            int n = colbase + t * 16 + lm;
#pragma unroll
            for (int j = 0; j < 4; ++j) {
                int m = rt * 16 + lk * 4 + j;
                float v = acc[t][j];
                if (n < 64) {
                    OUTY[(size_t)m * 64 + n] = (unsigned short)f2bf(v);
                } else {
                    v += bias[n - 64];
                    OUTR[(size_t)m * 64 + (n - 64)] = (unsigned short)f2bf(v);
                }
            }
        }
    }
}

// ---------------- pooling (batch is sorted) ----------------

__global__ void pool_kernel(const float* __restrict__ H, const int* __restrict__ batch,
                            float* __restrict__ G, int n) {
    const int CHUNK = 128;
    int f = threadIdx.x;  // 64 threads
    int start = blockIdx.x * CHUNK;
    if (start >= n) return;
    int end = start + CHUNK; if (end > n) end = n;
    int cur = batch[start];
    float acc = 0.f;
    for (int i = start; i < end; ++i) {
        int b = batch[i];
        if (b != cur) { atomicAdd(&G[(size_t)cur * 64 + f], acc); acc = 0.f; cur = b; }
        acc += H[(size_t)i * 64 + f];
    }
    atomicAdd(&G[(size_t)cur * 64 + f], acc);
}

// ---------------- MLP head + log_softmax ----------------

__global__ void mlp_head(const float* __restrict__ G, const float* __restrict__ fc1w,
                         const float* __restrict__ fc1b, const float* __restrict__ fc2w,
                         const float* __restrict__ fc2b, float* __restrict__ out) {
    int g = blockIdx.x;
    int t = threadIdx.x;  // 64
    __shared__ float gr[64], tt[64], sc[32], red[2];
    gr[t] = G[(size_t)g * 64 + t];
    __syncthreads();
    float acc = fc1b[t];
#pragma unroll
    for (int k = 0; k < 64; ++k) acc += gr[k] * fc1w[t * 64 + k];
    tt[t] = fmaxf(acc, 0.f);
    __syncthreads();
    if (t < 32) {
        float s = fc2b[t];
#pragma unroll
        for (int k = 0; k < 64; ++k) s += tt[k] * fc2w[t * 64 + k];
        sc[t] = s;
    }
    __syncthreads();
    if (t == 0) {
        float mx = sc[0];
        for (int c = 1; c < 32; ++c) mx = fmaxf(mx, sc[c]);
        float sum = 0.f;
        for (int c = 0; c < 32; ++c) sum += expf(sc[c] - mx);
        red[0] = mx; red[1] = logf(sum);
    }
    __syncthreads();
    if (t < 32) out[(size_t)g * 32 + t] = sc[t] - red[0] - red[1];
}

// ---------------- launch ----------------

extern "C" void kernel_launch(void* const* d_in, const int* in_sizes, int n_in,
                              void* d_out, int out_size, void* d_ws, size_t ws_size,
                              hipStream_t stream) {
    const float* x       = (const float*)d_in[0];
    const int*   edge    = (const int*)d_in[1];   // [2][E]: row0=src, row1=dst
    const int*   batch   = (const int*)d_in[2];
    const float* w1_rel  = (const float*)d_in[3];
    const float* b1      = (const float*)d_in[4];
    const float* w1_root = (const float*)d_in[5];
    const float* w2_rel  = (const float*)d_in[6];
    const float* b2      = (const float*)d_in[7];
    const float* w2_root = (const float*)d_in[8];
    const float* w3_rel  = (const float*)d_in[9];
    const float* b3      = (const float*)d_in[10];
    const float* w3_root = (const float*)d_in[11];
    const float* fc1w    = (const float*)d_in[12];
    const float* fc1b    = (const float*)d_in[13];
    const float* fc2w    = (const float*)d_in[14];
    const float* fc2b    = (const float*)d_in[15];
    float* out = (float*)d_out;

    char* p = (char*)d_ws;
    size_t used = 0;
    auto alloc = [&](size_t bytes) {
        char* r = p + used;
        used += (bytes + 255) & ~(size_t)255;
        return r;
    };
    int*            rowptr = (int*)alloc((N_NODES + 1) * sizeof(int));
    int*            cursor = (int*)alloc(N_NODES * sizeof(int));
    int*            csr    = (int*)alloc(N_EDGES * sizeof(int));
    int*            bsum   = (int*)alloc(SCAN_NB * sizeof(int));
    unsigned short* wbf    = (unsigned short*)alloc(57344 * sizeof(unsigned short));
    unsigned short* bufX   = (unsigned short*)alloc((size_t)N_NODES * 128 * 2);  // region X
    unsigned short* bufA   = (unsigned short*)alloc((size_t)N_NODES * 128 * 2);  // region A
    unsigned short* bufH   = (unsigned short*)alloc((size_t)N_NODES * 128 * 2);  // region H
    float*          G      = (float*)alloc((size_t)N_GRAPHS * 64 * sizeof(float));

    if (used > ws_size) return;  // clean bail instead of wild writes

    // bf16 weight views (r/o pairs contiguous -> dual-GEMM concat W)
    unsigned short* w1r_bf = wbf;          // [128][128]
    unsigned short* w1o_bf = wbf + 16384;  // [128][128]
    unsigned short* w2cat  = wbf + 32768;  // [128][128]: w2_rel ‖ w2_root
    unsigned short* w3cat  = wbf + 49152;  // [128][64] : w3_rel ‖ w3_root

    // Region aliasing timeline (tenant dead before reuse):
    unsigned short* XB    = bufX;                          // [N,128] bf16
    unsigned short* AGG1b = bufA;                          // [N,128] bf16
    unsigned short* H1b   = bufH;                          // [N,128] bf16
    unsigned short* Y2B   = bufX;                          // [N,64] bf16 (XB dead)
    unsigned short* ROOT2 = bufX + (size_t)N_NODES * 64;   // [N,64] bf16
    unsigned short* H2b   = bufA;                          // [N,64] bf16 (AGG1b dead)
    unsigned short* Y3B   = bufX;                          // [N,64] bf16 (Y2B dead)
    unsigned short* ROOT3 = bufX + (size_t)N_NODES * 64;   // [N,64] bf16 (ROOT2 dead)
    float*          H3    = (float*)bufH;                  // [N,64] f32 (H1b dead)

    // CSR build
    zero_int_kernel<<<(N_NODES + 256) / 256, 256, 0, stream>>>(rowptr, N_NODES + 1);
    hist_kernel<<<(N_EDGES + 255) / 256, 256, 0, stream>>>(edge, rowptr);
    scan_reduce_kernel<<<SCAN_NB, 256, 0, stream>>>(rowptr, bsum);
    scan_sums_kernel<<<1, 64, 0, stream>>>(bsum);
    scan_apply_kernel<<<SCAN_NB, 256, 0, stream>>>(rowptr, bsum, cursor);
    scatter_kernel<<<(N_EDGES + 255) / 256, 256, 0, stream>>>(edge, cursor, csr);

    // bf16 conversions
    f2bf_kernel<<<(N_NODES * 32 + 255) / 256, 256, 0, stream>>>(x, (uint2*)XB, N_NODES * 32);
    wconv_kernel<<<224, 256, 0, stream>>>(w1_rel, w1_root, w2_rel, w2_root, w3_rel, w3_root, wbf);

    int gblk = (N_NODES / 16 + 3) / 4;  // 782 blocks of 4 row-tiles

    // Layer 1: aggr1 = segsum(x); h1 = relu(aggr1@W1r + x@W1o + b1)  [concat-K MFMA]
    aggregate_u4<16, 0><<<(N_NODES + 15) / 16, 256, 0, stream>>>(XB, rowptr, csr, nullptr, AGG1b);
    gemm_mfma<4, 4, 2><<<gblk, 256, 0, stream>>>(AGG1b, w1r_bf, XB, w1o_bf, b1, H1b, 128);

    // Layer 2: {y2, root2} = h1@[W2r‖W2o] (+b2 on root); h2 = relu(segsum(y2)+root2)
    gemm_dual<4><<<gblk, 256, 0, stream>>>(H1b, w2cat, b2, Y2B, ROOT2);
    aggregate_u4<8, 1><<<(N_NODES + 31) / 32, 256, 0, stream>>>(Y2B, rowptr, csr, ROOT2, H2b);

    // Layer 3: {y3, root3} = h2@[W3r‖W3o] (+b3 on root); h3 = segsum(y3)+root3 (f32)
    gemm_dual<2><<<gblk, 256, 0, stream>>>(H2b, w3cat, b3, Y3B, ROOT3);
    aggregate_u4<8, 2><<<(N_NODES + 31) / 32, 256, 0, stream>>>(Y3B, rowptr, csr, ROOT3, H3);

    // Pool + head
    zero_float_kernel<<<(N_GRAPHS * 64 + 255) / 256, 256, 0, stream>>>(G, N_GRAPHS * 64);
    pool_kernel<<<(N_NODES + 127) / 128, 64, 0, stream>>>(H3, batch, G, N_NODES);
    mlp_head<<<N_GRAPHS, 64, 0, stream>>>(G, fc1w, fc1b, fc2w, fc2b, out);
}